// Round 11
// baseline (135.230 us; speedup 1.0000x reference)
//
#include <hip/hip_runtime.h>
#include <hip/hip_bf16.h>

#define EPSF 1e-5f

typedef __attribute__((ext_vector_type(8))) short short8;
typedef __attribute__((ext_vector_type(4))) float f32x4;

__device__ __forceinline__ int seg_of(int i, int o0, int o1, int o2) {
    return (i >= o0) + (i >= o1) + (i >= o2);
}

__device__ __forceinline__ unsigned short f2bf(float f) {
    unsigned int u = __float_as_uint(f);
    unsigned int r = (u + 0x7fffu + ((u >> 16) & 1u)) >> 16;
    return (unsigned short)r;
}
__device__ __forceinline__ unsigned int pack2bf(float a, float b) {
    return (unsigned int)f2bf(a) | ((unsigned int)f2bf(b) << 16);
}
__device__ __forceinline__ float bflo(unsigned int u) { return __uint_as_float(u << 16); }
__device__ __forceinline__ float bfhi(unsigned int u) { return __uint_as_float(u & 0xffff0000u); }

// stage 16 rows x 64 bf16 from global (row-major 64) into LDS (stride 72)
__device__ __forceinline__ void stage_rows_bf16(const unsigned short* __restrict__ src,
                                                unsigned short* dst, int l) {
    int row = l >> 2, cq = (l & 3) * 16;
    const short8* s = (const short8*)(src + (size_t)row*64 + cq);
    short8* d0 = (short8*)(dst + row*72 + cq);
    d0[0] = s[0];
    d0[1] = s[1];
}

// stage 16 rows x 64 f32 from global into bf16 LDS (stride 72)
__device__ __forceinline__ void stage_rows_f32(const float* __restrict__ src,
                                               unsigned short* dst, int l) {
    int row = l >> 2, cq = (l & 3) * 16;
    const float4* s = (const float4*)(src + (size_t)row*64 + cq);
    unsigned int* d = (unsigned int*)(dst + row*72 + cq);
    #pragma unroll
    for (int i = 0; i < 4; ++i) {
        float4 f = s[i];
        d[i*2]   = pack2bf(f.x, f.y);
        d[i*2+1] = pack2bf(f.z, f.w);
    }
}

// ---------------------------------------------------------------------------
// K0: fold BNs; build all bf16 B-fragments + folded biases; zero seg_max.
// ---------------------------------------------------------------------------
__global__ __launch_bounds__(256) void k_prep(
    const float* __restrict__ pe_W1, const float* __restrict__ pe_b1, const float* __restrict__ pe_bn,
    const float* __restrict__ pe_W2, const float* __restrict__ pe_b2,
    const float* __restrict__ we_W1, const float* __restrict__ we_b1, const float* __restrict__ we_bn,
    const float* __restrict__ we_W2,
    const float* __restrict__ cg_W1, const float* __restrict__ cg_b1, const float* __restrict__ cg_bn,
    const float* __restrict__ cg_W2,
    const float* __restrict__ Wq, const float* __restrict__ bq, const float* __restrict__ bnq,
    const float* __restrict__ Wk, const float* __restrict__ bk, const float* __restrict__ bnk,
    const float* __restrict__ Wv,
    float* __restrict__ peb1f, float* __restrict__ cvecg, float* __restrict__ cgb1f,
    float* __restrict__ biasqF, float* __restrict__ biaskF, float* __restrict__ cgW1cF,
    float* __restrict__ segm,
    unsigned short* __restrict__ WqF, unsigned short* __restrict__ WkF, unsigned short* __restrict__ WvF,
    unsigned short* __restrict__ weW1F, unsigned short* __restrict__ cgW1aF,
    unsigned short* __restrict__ cgW1bF, unsigned short* __restrict__ cgW2F,
    unsigned short* __restrict__ W1frag, unsigned short* __restrict__ Wcfrag,
    unsigned short* __restrict__ W2frag)
{
    int t = threadIdx.x;
    __shared__ float sc1[64], csc[64], sqv[64], skv[64], wsc[8], wsh[8];
    __shared__ float sWe[64][8], sWb[8], sWc[64][8];
    segm[t] = 0.f;
    if (t < 64) {
        float g = pe_bn[t], b = pe_bn[64+t], m = pe_bn[128+t], v = pe_bn[192+t];
        float s = g / sqrtf(v + EPSF);
        sc1[t] = s; peb1f[t] = pe_b1[t]*s + (b - m*s);
        g = cg_bn[t]; b = cg_bn[64+t]; m = cg_bn[128+t]; v = cg_bn[192+t];
        s = g / sqrtf(v + EPSF);
        csc[t] = s; cgb1f[t] = cg_b1[t]*s + (b - m*s);
        g = bnq[t]; b = bnq[64+t]; m = bnq[128+t]; v = bnq[192+t];
        s = g / sqrtf(v + EPSF);
        sqv[t] = s; biasqF[t] = bq[t]*s + (b - m*s);
        g = bnk[t]; b = bnk[64+t]; m = bnk[128+t]; v = bnk[192+t];
        s = g / sqrtf(v + EPSF);
        skv[t] = s; biaskF[t] = bk[t]*s + (b - m*s);
    }
    if (t < 8) {
        float g = we_bn[t], b = we_bn[8+t], m = we_bn[16+t], v = we_bn[24+t];
        float s = g / sqrtf(v + EPSF);
        wsc[t] = s; wsh[t] = b - m*s;
    }
    __syncthreads();
    for (int u = t; u < 512; u += 256) { int g = u & 7; sWe[u >> 3][g] = we_W1[u] * wsc[g]; }
    if (t < 8) sWb[t] = we_b1[t] * wsc[t] + wsh[t];
    __syncthreads();
    for (int u = t; u < 512; u += 256) {
        int h = u >> 3, g = u & 7;
        float a = 0.f;
        for (int c = 0; c < 64; ++c) a += pe_W2[h*64 + c] * sWe[c][g];
        sWc[h][g] = a;
    }
    if (t < 8) {
        float a = sWb[t];
        for (int c = 0; c < 64; ++c) a += pe_b2[c] * sWe[c][t];
        cvecg[t] = a;
    }
    __syncthreads();
    // 64x64 frags (8 tiles x 512)
    for (int u = t; u < 4096; u += 256) {
        int tile = u >> 9, l = (u >> 3) & 63, j = u & 7;
        int col = (tile >> 1)*16 + (l & 15);
        int kk  = (tile & 1)*32 + (l >> 4)*8 + j;
        WqF[u]    = f2bf(Wq[kk*64 + col] * sqv[col]);
        WkF[u]    = f2bf(Wk[kk*64 + col] * skv[col]);
        WvF[u]    = f2bf(Wv[kk*64 + col]);
        cgW1aF[u] = f2bf(cg_W1[kk*64 + col] * csc[col]);
        cgW1bF[u] = f2bf(cg_W1[(64 + kk)*64 + col] * csc[col]);
    }
    // 64->8/8->8 frags (2 tiles, cols padded to 16)
    for (int u = t; u < 1024; u += 256) {
        int tile = u >> 9, l = (u >> 3) & 63, j = u & 7;
        int col = l & 15;
        int kk  = tile*32 + (l >> 4)*8 + j;
        weW1F[u] = (col < 8) ? f2bf(sWe[kk][col]) : 0;
        cgW2F[u] = (col < 8) ? f2bf(cg_W2[kk*8 + col]) : 0;
    }
    // cgW1cF: rows 128..191 of cg_W1, BN-folded, f32
    for (int u = t; u < 4096; u += 256) {
        int k = u >> 6, c = u & 63;
        cgW1cF[u] = cg_W1[(128 + k)*64 + c] * csc[c];
    }
    // k_main frags
    {
        int ct = t >> 6, l = t & 63;
        int col = 16*ct + (l & 15), kg = l >> 4;
        #pragma unroll
        for (int j = 0; j < 8; ++j) {
            int k = kg*8 + j;
            float v = (k < 28) ? pe_W1[k*64 + col] * sc1[col] : 0.f;
            W1frag[ct*512 + l*8 + j] = f2bf(v);
        }
    }
    if (t < 128) {
        int kg = t >> 6, l = t & 63, g = l & 15;
        #pragma unroll
        for (int j = 0; j < 8; ++j) {
            int k = kg*32 + (l >> 4)*8 + j;
            float v = (g < 8) ? sWc[k][g] : 0.f;
            Wcfrag[kg*512 + l*8 + j] = f2bf(v);
        }
    }
    if (t < 64) {
        int l = t, g = l & 15;
        #pragma unroll
        for (int j = 0; j < 8; ++j) {
            float v = (l < 16 && g < 8) ? we_W2[j*8 + g] : 0.f;
            W2frag[l*8 + j] = f2bf(v);
        }
    }
}

// ---------------------------------------------------------------------------
// K1: MFMA q/k/v. Block = 4 waves x 16 rows = 64 rows, wave-private LDS.
// ---------------------------------------------------------------------------
__global__ __launch_bounds__(256) void k_qkv(
    const float* __restrict__ feat, const int* __restrict__ offs,
    const unsigned short* __restrict__ WqF, const unsigned short* __restrict__ WkF,
    const unsigned short* __restrict__ WvF, const unsigned short* __restrict__ weW1F,
    const float* __restrict__ biasqF, const float* __restrict__ biaskF,
    const float* __restrict__ bv,
    unsigned short* __restrict__ v_bf, unsigned short* __restrict__ q_bf,
    float* __restrict__ kw, float* __restrict__ qw, float* __restrict__ seg_max)
{
    __shared__ unsigned short sF[4][16*72];
    __shared__ unsigned short sQ[4][16*72];
    __shared__ unsigned short sK[4][16*72];
    __shared__ float sSeg[64];

    int t = threadIdx.x, w = t >> 6, l = t & 63;
    int lc = l & 15, lg = l >> 4;
    int rblk = blockIdx.x * 64;
    int r0 = rblk + w * 16;
    int o0 = offs[0], o1 = offs[1], o2 = offs[2];
    bool fast = seg_of(rblk, o0,o1,o2) == seg_of(rblk + 63, o0,o1,o2);

    if (t < 64) sSeg[t] = 0.f;
    __syncthreads();

    stage_rows_f32(feat + (size_t)r0*64, sF[w], l);
    short8 a0 = *(const short8*)(sF[w] + lc*72 + lg*8);
    short8 a1 = *(const short8*)(sF[w] + lc*72 + 32 + lg*8);

    float bqc[4], bkc[4], bvc[4];
    #pragma unroll
    for (int ct = 0; ct < 4; ++ct) {
        bqc[ct] = biasqF[ct*16 + lc];
        bkc[ct] = biaskF[ct*16 + lc];
        bvc[ct] = bv[ct*16 + lc];
    }

    // ---- q ----
    #pragma unroll
    for (int ct = 0; ct < 4; ++ct) {
        f32x4 z = {0.f,0.f,0.f,0.f};
        short8 b0 = *(const short8*)(WqF + (ct*2+0)*512 + l*8);
        short8 b1 = *(const short8*)(WqF + (ct*2+1)*512 + l*8);
        f32x4 c = __builtin_amdgcn_mfma_f32_16x16x32_bf16(a0, b0, z, 0,0,0);
        c = __builtin_amdgcn_mfma_f32_16x16x32_bf16(a1, b1, c, 0,0,0);
        float cmax = 0.f;
        #pragma unroll
        for (int reg = 0; reg < 4; ++reg) {
            float qv = fmaxf(c[reg] + bqc[ct], 0.f);
            sQ[w][(lg*4 + reg)*72 + ct*16 + lc] = f2bf(qv);
            if (fast) cmax = fmaxf(cmax, qv);
            else atomicMax((unsigned int*)&seg_max[seg_of(r0 + lg*4 + reg,o0,o1,o2)*64 + ct*16 + lc],
                           __float_as_uint(qv));
        }
        if (fast) {
            cmax = fmaxf(cmax, __shfl_xor(cmax, 16));
            cmax = fmaxf(cmax, __shfl_xor(cmax, 32));
            if (lg == 0)
                atomicMax((unsigned int*)&sSeg[ct*16 + lc], __float_as_uint(cmax));
        }
    }
    // ---- seg-max combine early ----
    __syncthreads();
    if (fast && t < 64)
        atomicMax((unsigned int*)&seg_max[seg_of(rblk,o0,o1,o2)*64 + t],
                  __float_as_uint(sSeg[t]));

    // ---- k ----
    #pragma unroll
    for (int ct = 0; ct < 4; ++ct) {
        f32x4 z = {0.f,0.f,0.f,0.f};
        short8 b0 = *(const short8*)(WkF + (ct*2+0)*512 + l*8);
        short8 b1 = *(const short8*)(WkF + (ct*2+1)*512 + l*8);
        f32x4 c = __builtin_amdgcn_mfma_f32_16x16x32_bf16(a0, b0, z, 0,0,0);
        c = __builtin_amdgcn_mfma_f32_16x16x32_bf16(a1, b1, c, 0,0,0);
        #pragma unroll
        for (int reg = 0; reg < 4; ++reg)
            sK[w][(lg*4 + reg)*72 + ct*16 + lc] = f2bf(fmaxf(c[reg] + bkc[ct], 0.f));
    }
    // ---- v (staged bf16 into sF, which is dead now) ----
    #pragma unroll
    for (int ct = 0; ct < 4; ++ct) {
        f32x4 z = {0.f,0.f,0.f,0.f};
        short8 b0 = *(const short8*)(WvF + (ct*2+0)*512 + l*8);
        short8 b1 = *(const short8*)(WvF + (ct*2+1)*512 + l*8);
        f32x4 c = __builtin_amdgcn_mfma_f32_16x16x32_bf16(a0, b0, z, 0,0,0);
        c = __builtin_amdgcn_mfma_f32_16x16x32_bf16(a1, b1, c, 0,0,0);
        #pragma unroll
        for (int reg = 0; reg < 4; ++reg)
            sF[w][(lg*4 + reg)*72 + ct*16 + lc] = f2bf(c[reg] + bvc[ct]);
    }
    // ---- kw / qw via MFMA (K=64 -> 8 cols) ----
    {
        short8 wb0 = *(const short8*)(weW1F + l*8);
        short8 wb1 = *(const short8*)(weW1F + 512 + l*8);
        short8 aq0 = *(const short8*)(sQ[w] + lc*72 + lg*8);
        short8 aq1 = *(const short8*)(sQ[w] + lc*72 + 32 + lg*8);
        short8 ak0 = *(const short8*)(sK[w] + lc*72 + lg*8);
        short8 ak1 = *(const short8*)(sK[w] + lc*72 + 32 + lg*8);
        f32x4 z = {0.f,0.f,0.f,0.f};
        f32x4 cq = __builtin_amdgcn_mfma_f32_16x16x32_bf16(aq0, wb0, z, 0,0,0);
        cq = __builtin_amdgcn_mfma_f32_16x16x32_bf16(aq1, wb1, cq, 0,0,0);
        f32x4 ck = __builtin_amdgcn_mfma_f32_16x16x32_bf16(ak0, wb0, z, 0,0,0);
        ck = __builtin_amdgcn_mfma_f32_16x16x32_bf16(ak1, wb1, ck, 0,0,0);
        if (lc < 8) {
            #pragma unroll
            for (int reg = 0; reg < 4; ++reg) {
                qw[(size_t)(r0 + lg*4 + reg)*8 + lc] = cq[reg];
                kw[(size_t)(r0 + lg*4 + reg)*8 + lc] = ck[reg];
            }
        }
    }
    // ---- q_bf / v_bf global writes ----
    #pragma unroll
    for (int rep = 0; rep < 2; ++rep) {
        int row = (l >> 3) + rep*8;
        int ch = (l & 7) * 8;
        short8 vq = *(const short8*)(sQ[w] + row*72 + ch);
        *(short8*)(q_bf + (size_t)(r0 + row)*64 + ch) = vq;
        short8 vv = *(const short8*)(sF[w] + row*72 + ch);
        *(short8*)(v_bf + (size_t)(r0 + row)*64 + ch) = vv;
    }
}

// ---------------------------------------------------------------------------
// K3 (fused): gate (phase A, incl. per-block gseg2) + PE/softmax/einsum.
// LDS 24.1 KB -> 6 blocks/CU. xe rows live in VGPRs; per-rt wave staging.
// ---------------------------------------------------------------------------
__global__ __launch_bounds__(256, 6) void k_main(
    const float* __restrict__ coord, const int* __restrict__ ridx,
    const unsigned short* __restrict__ v_bf, const unsigned short* __restrict__ q_bf,
    const float* __restrict__ kw, const float* __restrict__ qw,
    const float* __restrict__ peb1f, const float* __restrict__ cvecg,
    const float* __restrict__ we_b2, const float* __restrict__ cg_b2,
    const float* __restrict__ seg_max, const float* __restrict__ cgW1cF,
    const float* __restrict__ cgb1f, const int* __restrict__ offs,
    const unsigned short* __restrict__ W1frag, const unsigned short* __restrict__ Wcfrag,
    const unsigned short* __restrict__ W2frag,
    const unsigned short* __restrict__ cgW1aF, const unsigned short* __restrict__ cgW1bF,
    const unsigned short* __restrict__ cgW2F,
    float* __restrict__ out)
{
    __shared__ __align__(16) unsigned short sXe[4*640];    // 5120 B per-rt xe staging
    __shared__ __align__(16) unsigned short sA2[4][16*72]; // 9216 B per-wave H1
    __shared__ __align__(16) unsigned short sU[3584];      // 7168 B union:
        // phase A: sQg=sU[0..1152), sN=sU[1152..2304), sHg=sU[2304..3456)
        // phase B: sAh2=[4][128]=sU[0..512), sAttnB [16pt][8gh][24]=sU[512..3584)
    __shared__ float sGate[16][9];                         // 576 B
    __shared__ float sGseg[4][64];                         // 1024 B
    __shared__ int sIds[256];                              // 1024 B

    int t = threadIdx.x, w = t >> 6, l = t & 63;
    int lc = l & 15, lg = l >> 4;
    int n0 = blockIdx.x * 16;
    int o0 = offs[0], o1 = offs[1], o2 = offs[2];

    unsigned short* sQg = sU;
    unsigned short* sN  = sU + 1152;
    unsigned short* sHg = sU + 2304;
    unsigned short* sAh2w  = sU + w*128;
    unsigned short* sAttnB = sU + 512;

    // ---- step 1: ids + own xe row (registers) + per-block gseg2 ----
    int id = ridx[(size_t)n0*16 + t];
    sIds[t] = id;
    int ids = max(id, 0);
    int nself = n0 + (t >> 4);
    unsigned int xr[16];
    {
        float cx = coord[nself*3], cy = coord[nself*3+1], cz = coord[nself*3+2];
        float dx = coord[ids*3]   - cx;
        float dy = coord[ids*3+1] - cy;
        float dz = coord[ids*3+2] - cz;
        float dist = sqrtf(dx*dx + dy*dy + dz*dz);
        xr[0] = pack2bf(dx, dy);
        xr[1] = pack2bf(dz, dist);
        float sx, cx2, sy, cy2, sz, cz2;
        __sincosf(dx * 3.14159265358979f, &sx, &cx2);
        __sincosf(dy * 3.14159265358979f, &sy, &cy2);
        __sincosf(dz * 3.14159265358979f, &sz, &cz2);
        xr[2]  = pack2bf(sx, sy);
        xr[3]  = pack2bf(cx2, cy2);
        xr[10] = pack2bf(sz, cz2);
        #pragma unroll
        for (int fi = 1; fi < 4; ++fi) {
            float nsx = 2.f*sx*cx2, ncx = fmaf(-2.f*sx, sx, 1.f);
            float nsy = 2.f*sy*cy2, ncy = fmaf(-2.f*sy, sy, 1.f);
            float nsz = 2.f*sz*cz2, ncz = fmaf(-2.f*sz, sz, 1.f);
            xr[2 + 2*fi] = pack2bf(nsx, nsy);
            xr[3 + 2*fi] = pack2bf(ncx, ncy);
            xr[10 + fi]  = pack2bf(nsz, ncz);
            sx = nsx; cx2 = ncx; sy = nsy; cy2 = ncy; sz = nsz; cz2 = ncz;
        }
        xr[14] = 0u; xr[15] = 0u;
    }
    if (t < 64) stage_rows_bf16(q_bf + (size_t)n0*64, sQg, t);
    // gseg2 per block: thread (s=w, c=l); coalesced cgW1cF rows, scalar seg_max
    {
        float a = cgb1f[l];
        #pragma unroll 8
        for (int j = 0; j < 64; ++j)
            a += seg_max[w*64 + j] * cgW1cF[j*64 + l];
        sGseg[w][l] = a;
    }
    __syncthreads();   // sIds + sQg + sGseg ready

    // ---- step 2: neighbor-max gather (lane = point p, col-slice s) ----
    {
        int p = t >> 4, s = t & 15;
        const int* ip = &sIds[p*16];
        float m0 = 0.f, m1 = 0.f, m2 = 0.f, m3 = 0.f;
        #pragma unroll
        for (int kb = 0; kb < 16; kb += 4) {
            uint2 u[4];
            #pragma unroll
            for (int j = 0; j < 4; ++j) {
                int idn = max(ip[kb + j], 0);
                u[j] = *(const uint2*)(q_bf + (size_t)idn*64 + s*4);
            }
            #pragma unroll
            for (int j = 0; j < 4; ++j) {
                m0 = fmaxf(m0, bflo(u[j].x)); m1 = fmaxf(m1, bfhi(u[j].x));
                m2 = fmaxf(m2, bflo(u[j].y)); m3 = fmaxf(m3, bfhi(u[j].y));
            }
        }
        unsigned int* d = (unsigned int*)(sN + p*72 + s*4);
        d[0] = pack2bf(m0, m1);
        d[1] = pack2bf(m2, m3);
    }
    __syncthreads();   // sN ready

    // ---- step 3: gate H1 (wave w owns output col-tile ct=w) ----
    {
        short8 a0 = *(const short8*)(sQg + lc*72 + lg*8);
        short8 a1 = *(const short8*)(sQg + lc*72 + 32 + lg*8);
        short8 nv0 = *(const short8*)(sN + lc*72 + lg*8);
        short8 nv1 = *(const short8*)(sN + lc*72 + 32 + lg*8);
        f32x4 c4;
        #pragma unroll
        for (int reg = 0; reg < 4; ++reg)
            c4[reg] = sGseg[seg_of(n0 + lg*4 + reg, o0, o1, o2)][w*16 + lc];
        short8 b0 = *(const short8*)(cgW1aF + (w*2+0)*512 + l*8);
        short8 b1 = *(const short8*)(cgW1aF + (w*2+1)*512 + l*8);
        c4 = __builtin_amdgcn_mfma_f32_16x16x32_bf16(a0, b0, c4, 0,0,0);
        c4 = __builtin_amdgcn_mfma_f32_16x16x32_bf16(a1, b1, c4, 0,0,0);
        short8 b2 = *(const short8*)(cgW1bF + (w*2+0)*512 + l*8);
        short8 b3 = *(const short8*)(cgW1bF + (w*2+1)*512 + l*8);
        c4 = __builtin_amdgcn_mfma_f32_16x16x32_bf16(nv0, b2, c4, 0,0,0);
        c4 = __builtin_amdgcn_mfma_f32_16x16x32_bf16(nv1, b3, c4, 0,0,0);
        #pragma unroll
        for (int reg = 0; reg < 4; ++reg)
            sHg[(lg*4 + reg)*72 + w*16 + lc] = f2bf(fmaxf(c4[reg], 0.f));
    }
    __syncthreads();   // sHg ready

    // ---- step 4: final gate MFMA (wave 0 only) ----
    if (w == 0) {
        short8 ah0 = *(const short8*)(sHg + lc*72 + lg*8);
        short8 ah1 = *(const short8*)(sHg + lc*72 + 32 + lg*8);
        short8 w0f = *(const short8*)(cgW2F + l*8);
        short8 w1f = *(const short8*)(cgW2F + 512 + l*8);
        float bg = cg_b2[lc & 7];
        f32x4 cg;
        #pragma unroll
        for (int reg = 0; reg < 4; ++reg) cg[reg] = bg;
        cg = __builtin_amdgcn_mfma_f32_16x16x32_bf16(ah0, w0f, cg, 0,0,0);
        cg = __builtin_amdgcn_mfma_f32_16x16x32_bf16(ah1, w1f, cg, 0,0,0);
        if (lc < 8) {
            #pragma unroll
            for (int reg = 0; reg < 4; ++reg)
                sGate[lg*4 + reg][lc] = 1.f / (1.f + __expf(-cg[reg]));
        }
    }
    __syncthreads();   // sGate ready; phase-A scratch dead -> reuse

    // ---- phase B: per-wave PE pipeline ----
    int g7 = lc & 7;
    short8 bW1[4], bWc[2], bW2;
    #pragma unroll
    for (int ct = 0; ct < 4; ++ct) bW1[ct] = *(const short8*)(W1frag + ct*512 + l*8);
    bWc[0] = *(const short8*)(Wcfrag + l*8);
    bWc[1] = *(const short8*)(Wcfrag + 512 + l*8);
    bW2 = *(const short8*)(W2frag + l*8);

    float bias1[4];
    #pragma unroll
    for (int ct = 0; ct < 4; ++ct) bias1[ct] = peb1f[16*ct + lc];
    float cvec_g = cvecg[g7];
    float bias3 = we_b2[g7];
    unsigned short* sXw = sXe + w*640;

    #pragma unroll
    for (int rt = 0; rt < 4; ++rt) {
        int n = n0 + w*4 + rt;
        // stage this tile's xe rows from registers (lanes lg==rt own them)
        if (lg == rt) {
            unsigned int* dst = (unsigned int*)(sXw + lc*40);
            #pragma unroll
            for (int i = 0; i < 16; ++i) dst[i] = xr[i];
        }
        short8 a1 = *(const short8*)(sXw + lc*40 + lg*8);
        f32x4 c1[4];
        #pragma unroll
        for (int ct = 0; ct < 4; ++ct) {
            f32x4 z = {0.f, 0.f, 0.f, 0.f};
            c1[ct] = __builtin_amdgcn_mfma_f32_16x16x32_bf16(a1, bW1[ct], z, 0, 0, 0);
        }
        #pragma unroll
        for (int ct = 0; ct < 4; ++ct) {
            #pragma unroll
            for (int reg = 0; reg < 4; ++reg) {
                float h1 = fmaxf(c1[ct][reg] + bias1[ct], 0.f);
                sA2[w][(lg*4 + reg)*72 + 16*ct + lc] = f2bf(h1);
            }
        }
        int ids_r[4];
        #pragma unroll
        for (int reg = 0; reg < 4; ++reg) ids_r[reg] = sIds[w*64 + rt*16 + lg*4 + reg];
        float qwv = qw[(size_t)n*8 + g7];
        f32x4 c2;
        #pragma unroll
        for (int reg = 0; reg < 4; ++reg)
            c2[reg] = kw[(size_t)max(ids_r[reg],0)*8 + g7] - qwv + cvec_g;
        short8 a20 = *(const short8*)(sA2[w] + lc*72 + lg*8);
        short8 a21 = *(const short8*)(sA2[w] + lc*72 + 32 + lg*8);
        c2 = __builtin_amdgcn_mfma_f32_16x16x32_bf16(a20, bWc[0], c2, 0, 0, 0);
        c2 = __builtin_amdgcn_mfma_f32_16x16x32_bf16(a21, bWc[1], c2, 0, 0, 0);
        if (lc < 8) {
            #pragma unroll
            for (int reg = 0; reg < 4; ++reg)
                sAh2w[(lg*4 + reg)*8 + lc] = f2bf(fmaxf(c2[reg], 0.f));
        }
        short8 a3 = {0,0,0,0,0,0,0,0};
        if (l < 16) a3 = *(const short8*)(sAh2w + lc*8);
        f32x4 c3;
        #pragma unroll
        for (int reg = 0; reg < 4; ++reg) c3[reg] = bias3;
        c3 = __builtin_amdgcn_mfma_f32_16x16x32_bf16(a3, bW2, c3, 0, 0, 0);
        float gv = sGate[w*4 + rt][g7];
        float lgt[4];
        #pragma unroll
        for (int reg = 0; reg < 4; ++reg) lgt[reg] = c3[reg] * gv;
        float m = fmaxf(fmaxf(lgt[0], lgt[1]), fmaxf(lgt[2], lgt[3]));
        m = fmaxf(m, __shfl_xor(m, 16));
        m = fmaxf(m, __shfl_xor(m, 32));
        float e[4], s = 0.f;
        #pragma unroll
        for (int reg = 0; reg < 4; ++reg) { e[reg] = __expf(lgt[reg] - m); s += e[reg]; }
        s += __shfl_xor(s, 16);
        s += __shfl_xor(s, 32);
        float inv = 1.f / s;
        if (lc < 8) {
            float av[4];
            #pragma unroll
            for (int reg = 0; reg < 4; ++reg) {
                int idv = ids_r[reg];
                float mf = (idv >= 0) ? 1.f : ((idv == -1) ? 0.f : -1.f);
                av[reg] = e[reg] * inv * mf;
            }
            // layout [point][gh=lc][k2=lg*4+reg], stride 24
            unsigned int* d = (unsigned int*)(sAttnB + ((w*4 + rt)*8 + lc)*24 + lg*4);
            d[0] = pack2bf(av[0], av[1]);
            d[1] = pack2bf(av[2], av[3]);
        }
    }

    // ---- einsum: attn via 2x b128, late v-gather ----
    {
        int p = lg, kk = lc;
        int n2 = n0 + w*4 + p;
        const unsigned short* ab = sAttnB + ((w*4 + p)*8 + (kk >> 1))*24;
        short8 aa0 = *(const short8*)(ab);
        short8 aa1 = *(const short8*)(ab + 8);
        float4 o = make_float4(0.f, 0.f, 0.f, 0.f);
        #pragma unroll
        for (int k2 = 0; k2 < 16; ++k2) {
            int id2 = max(sIds[w*64 + p*16 + k2], 0);
            unsigned short ar = (k2 < 8) ? (unsigned short)aa0[k2] : (unsigned short)aa1[k2-8];
            float a = bflo((unsigned int)ar);
            uint2 u = *(const uint2*)(v_bf + (size_t)id2*64 + kk*4);
            o.x += a * bflo(u.x); o.y += a * bfhi(u.x);
            o.z += a * bflo(u.y); o.w += a * bfhi(u.y);
        }
        *(float4*)(out + (size_t)n2*64 + kk*4) = o;
    }
}

// ---------------------------------------------------------------------------
extern "C" void kernel_launch(void* const* d_in, const int* in_sizes, int n_in,
                              void* d_out, int out_size, void* d_ws, size_t ws_size,
                              hipStream_t stream)
{
    const float* feat  = (const float*)d_in[0];
    const float* coord = (const float*)d_in[1];
    const int*   ridx  = (const int*)d_in[2];
    const int*   offs  = (const int*)d_in[3];
    const float* Wq = (const float*)d_in[4];  const float* bq = (const float*)d_in[5];  const float* bnq = (const float*)d_in[6];
    const float* Wk = (const float*)d_in[7];  const float* bk = (const float*)d_in[8];  const float* bnk = (const float*)d_in[9];
    const float* Wv = (const float*)d_in[10]; const float* bv = (const float*)d_in[11];
    const float* pe_W1 = (const float*)d_in[12]; const float* pe_b1 = (const float*)d_in[13]; const float* pe_bn = (const float*)d_in[14];
    const float* pe_W2 = (const float*)d_in[15]; const float* pe_b2 = (const float*)d_in[16];
    const float* we_W1 = (const float*)d_in[17]; const float* we_b1 = (const float*)d_in[18]; const float* we_bn = (const float*)d_in[19];
    const float* we_W2 = (const float*)d_in[20]; const float* we_b2 = (const float*)d_in[21];
    const float* cg_W1 = (const float*)d_in[22]; const float* cg_b1 = (const float*)d_in[23]; const float* cg_bn = (const float*)d_in[24];
    const float* cg_W2 = (const float*)d_in[25]; const float* cg_b2 = (const float*)d_in[26];
    float* out = (float*)d_out;
    int N = in_sizes[0] / 64;

    // bf16 tables first (16B aligned at ws base)
    unsigned short* v_bf = (unsigned short*)d_ws;               // N*64
    unsigned short* q_bf = v_bf + (size_t)N*64;                 // N*64
    float* kwp   = (float*)(q_bf + (size_t)N*64);               // N*8
    float* qwp   = kwp + (size_t)N*8;                           // N*8
    float* segm  = qwp + (size_t)N*8;                           // 256
    float* peb1f = segm + 256;                                  // 64
    float* cvecg = peb1f + 64;                                  // 8
    float* cgb1f = cvecg + 8;                                   // 64
    float* biasqF= cgb1f + 64;                                  // 64
    float* biaskF= biasqF + 64;                                 // 64
    float* pad0  = biaskF + 64;                                 // 56 pad
    float* cgW1cF= pad0 + 56;                                   // 4096
    unsigned short* WqF     = (unsigned short*)(cgW1cF + 4096); // 4096
    unsigned short* WkF     = WqF + 4096;                       // 4096
    unsigned short* WvF     = WkF + 4096;                       // 4096
    unsigned short* weW1F   = WvF + 4096;                       // 1024
    unsigned short* cgW1aF  = weW1F + 1024;                     // 4096
    unsigned short* cgW1bF  = cgW1aF + 4096;                    // 4096
    unsigned short* cgW2F   = cgW1bF + 4096;                    // 1024
    unsigned short* W1frag  = cgW2F + 1024;                     // 2048
    unsigned short* Wcfrag  = W1frag + 2048;                    // 1024
    unsigned short* W2frag  = Wcfrag + 1024;                    // 512

    k_prep<<<1, 256, 0, stream>>>(pe_W1, pe_b1, pe_bn, pe_W2, pe_b2,
                                  we_W1, we_b1, we_bn, we_W2,
                                  cg_W1, cg_b1, cg_bn, cg_W2,
                                  Wq, bq, bnq, Wk, bk, bnk, Wv,
                                  peb1f, cvecg, cgb1f, biasqF, biaskF, cgW1cF, segm,
                                  WqF, WkF, WvF, weW1F, cgW1aF, cgW1bF, cgW2F,
                                  W1frag, Wcfrag, W2frag);
    k_qkv<<<N/64, 256, 0, stream>>>(feat, offs, WqF, WkF, WvF, weW1F,
                                    biasqF, biaskF, bv,
                                    v_bf, q_bf, kwp, qwp, segm);
    k_main<<<N/16, 256, 0, stream>>>(coord, ridx, v_bf, q_bf, kwp, qwp,
                                     peb1f, cvecg, we_b2, cg_b2,
                                     segm, cgW1cF, cgb1f, offs,
                                     W1frag, Wcfrag, W2frag,
                                     cgW1aF, cgW1bF, cgW2F, out);
}

// Round 12
// 134.022 us; speedup vs baseline: 1.0090x; 1.0090x over previous
//
#include <hip/hip_runtime.h>
#include <hip/hip_bf16.h>

#define EPSF 1e-5f

typedef __attribute__((ext_vector_type(8))) short short8;
typedef __attribute__((ext_vector_type(4))) float f32x4;

__device__ __forceinline__ int seg_of(int i, int o0, int o1, int o2) {
    return (i >= o0) + (i >= o1) + (i >= o2);
}

__device__ __forceinline__ unsigned short f2bf(float f) {
    unsigned int u = __float_as_uint(f);
    unsigned int r = (u + 0x7fffu + ((u >> 16) & 1u)) >> 16;
    return (unsigned short)r;
}
__device__ __forceinline__ unsigned int pack2bf(float a, float b) {
    return (unsigned int)f2bf(a) | ((unsigned int)f2bf(b) << 16);
}
__device__ __forceinline__ float bflo(unsigned int u) { return __uint_as_float(u << 16); }
__device__ __forceinline__ float bfhi(unsigned int u) { return __uint_as_float(u & 0xffff0000u); }

// stage 16 rows x 64 bf16 from global (row-major 64) into LDS (stride 72)
__device__ __forceinline__ void stage_rows_bf16(const unsigned short* __restrict__ src,
                                                unsigned short* dst, int l) {
    int row = l >> 2, cq = (l & 3) * 16;
    const short8* s = (const short8*)(src + (size_t)row*64 + cq);
    short8* d0 = (short8*)(dst + row*72 + cq);
    d0[0] = s[0];
    d0[1] = s[1];
}

// stage 16 rows x 64 f32 from global into bf16 LDS (stride 72)
__device__ __forceinline__ void stage_rows_f32(const float* __restrict__ src,
                                               unsigned short* dst, int l) {
    int row = l >> 2, cq = (l & 3) * 16;
    const float4* s = (const float4*)(src + (size_t)row*64 + cq);
    unsigned int* d = (unsigned int*)(dst + row*72 + cq);
    #pragma unroll
    for (int i = 0; i < 4; ++i) {
        float4 f = s[i];
        d[i*2]   = pack2bf(f.x, f.y);
        d[i*2+1] = pack2bf(f.z, f.w);
    }
}

// ---------------------------------------------------------------------------
// K0: fold BNs; build all bf16 B-fragments + folded biases; zero seg_max.
// ---------------------------------------------------------------------------
__global__ __launch_bounds__(256) void k_prep(
    const float* __restrict__ pe_W1, const float* __restrict__ pe_b1, const float* __restrict__ pe_bn,
    const float* __restrict__ pe_W2, const float* __restrict__ pe_b2,
    const float* __restrict__ we_W1, const float* __restrict__ we_b1, const float* __restrict__ we_bn,
    const float* __restrict__ we_W2,
    const float* __restrict__ cg_W1, const float* __restrict__ cg_b1, const float* __restrict__ cg_bn,
    const float* __restrict__ cg_W2,
    const float* __restrict__ Wq, const float* __restrict__ bq, const float* __restrict__ bnq,
    const float* __restrict__ Wk, const float* __restrict__ bk, const float* __restrict__ bnk,
    const float* __restrict__ Wv,
    float* __restrict__ peb1f, float* __restrict__ cvecg, float* __restrict__ cgb1f,
    float* __restrict__ biasqF, float* __restrict__ biaskF, float* __restrict__ cgW1cF,
    float* __restrict__ segm,
    unsigned short* __restrict__ WqF, unsigned short* __restrict__ WkF, unsigned short* __restrict__ WvF,
    unsigned short* __restrict__ weW1F, unsigned short* __restrict__ cgW1aF,
    unsigned short* __restrict__ cgW1bF, unsigned short* __restrict__ cgW2F,
    unsigned short* __restrict__ W1frag, unsigned short* __restrict__ Wcfrag,
    unsigned short* __restrict__ W2frag)
{
    int t = threadIdx.x;
    __shared__ float sc1[64], csc[64], sqv[64], skv[64], wsc[8], wsh[8];
    __shared__ float sWe[64][8], sWb[8], sWc[64][8];
    segm[t] = 0.f;
    if (t < 64) {
        float g = pe_bn[t], b = pe_bn[64+t], m = pe_bn[128+t], v = pe_bn[192+t];
        float s = g / sqrtf(v + EPSF);
        sc1[t] = s; peb1f[t] = pe_b1[t]*s + (b - m*s);
        g = cg_bn[t]; b = cg_bn[64+t]; m = cg_bn[128+t]; v = cg_bn[192+t];
        s = g / sqrtf(v + EPSF);
        csc[t] = s; cgb1f[t] = cg_b1[t]*s + (b - m*s);
        g = bnq[t]; b = bnq[64+t]; m = bnq[128+t]; v = bnq[192+t];
        s = g / sqrtf(v + EPSF);
        sqv[t] = s; biasqF[t] = bq[t]*s + (b - m*s);
        g = bnk[t]; b = bnk[64+t]; m = bnk[128+t]; v = bnk[192+t];
        s = g / sqrtf(v + EPSF);
        skv[t] = s; biaskF[t] = bk[t]*s + (b - m*s);
    }
    if (t < 8) {
        float g = we_bn[t], b = we_bn[8+t], m = we_bn[16+t], v = we_bn[24+t];
        float s = g / sqrtf(v + EPSF);
        wsc[t] = s; wsh[t] = b - m*s;
    }
    __syncthreads();
    for (int u = t; u < 512; u += 256) { int g = u & 7; sWe[u >> 3][g] = we_W1[u] * wsc[g]; }
    if (t < 8) sWb[t] = we_b1[t] * wsc[t] + wsh[t];
    __syncthreads();
    for (int u = t; u < 512; u += 256) {
        int h = u >> 3, g = u & 7;
        float a = 0.f;
        for (int c = 0; c < 64; ++c) a += pe_W2[h*64 + c] * sWe[c][g];
        sWc[h][g] = a;
    }
    if (t < 8) {
        float a = sWb[t];
        for (int c = 0; c < 64; ++c) a += pe_b2[c] * sWe[c][t];
        cvecg[t] = a;
    }
    __syncthreads();
    // 64x64 frags (8 tiles x 512)
    for (int u = t; u < 4096; u += 256) {
        int tile = u >> 9, l = (u >> 3) & 63, j = u & 7;
        int col = (tile >> 1)*16 + (l & 15);
        int kk  = (tile & 1)*32 + (l >> 4)*8 + j;
        WqF[u]    = f2bf(Wq[kk*64 + col] * sqv[col]);
        WkF[u]    = f2bf(Wk[kk*64 + col] * skv[col]);
        WvF[u]    = f2bf(Wv[kk*64 + col]);
        cgW1aF[u] = f2bf(cg_W1[kk*64 + col] * csc[col]);
        cgW1bF[u] = f2bf(cg_W1[(64 + kk)*64 + col] * csc[col]);
    }
    // 64->8/8->8 frags (2 tiles, cols padded to 16)
    for (int u = t; u < 1024; u += 256) {
        int tile = u >> 9, l = (u >> 3) & 63, j = u & 7;
        int col = l & 15;
        int kk  = tile*32 + (l >> 4)*8 + j;
        weW1F[u] = (col < 8) ? f2bf(sWe[kk][col]) : 0;
        cgW2F[u] = (col < 8) ? f2bf(cg_W2[kk*8 + col]) : 0;
    }
    // cgW1cF: rows 128..191 of cg_W1, BN-folded, f32
    for (int u = t; u < 4096; u += 256) {
        int k = u >> 6, c = u & 63;
        cgW1cF[u] = cg_W1[(128 + k)*64 + c] * csc[c];
    }
    // k_main frags
    {
        int ct = t >> 6, l = t & 63;
        int col = 16*ct + (l & 15), kg = l >> 4;
        #pragma unroll
        for (int j = 0; j < 8; ++j) {
            int k = kg*8 + j;
            float v = (k < 28) ? pe_W1[k*64 + col] * sc1[col] : 0.f;
            W1frag[ct*512 + l*8 + j] = f2bf(v);
        }
    }
    if (t < 128) {
        int kg = t >> 6, l = t & 63, g = l & 15;
        #pragma unroll
        for (int j = 0; j < 8; ++j) {
            int k = kg*32 + (l >> 4)*8 + j;
            float v = (g < 8) ? sWc[k][g] : 0.f;
            Wcfrag[kg*512 + l*8 + j] = f2bf(v);
        }
    }
    if (t < 64) {
        int l = t, g = l & 15;
        #pragma unroll
        for (int j = 0; j < 8; ++j) {
            float v = (l < 16 && g < 8) ? we_W2[j*8 + g] : 0.f;
            W2frag[l*8 + j] = f2bf(v);
        }
    }
}

// ---------------------------------------------------------------------------
// K1: MFMA q/k/v. Block = 4 waves x 16 rows = 64 rows, wave-private LDS.
// ---------------------------------------------------------------------------
__global__ __launch_bounds__(256) void k_qkv(
    const float* __restrict__ feat, const int* __restrict__ offs,
    const unsigned short* __restrict__ WqF, const unsigned short* __restrict__ WkF,
    const unsigned short* __restrict__ WvF, const unsigned short* __restrict__ weW1F,
    const float* __restrict__ biasqF, const float* __restrict__ biaskF,
    const float* __restrict__ bv,
    unsigned short* __restrict__ v_bf, unsigned short* __restrict__ q_bf,
    float* __restrict__ kw, float* __restrict__ qw, float* __restrict__ seg_max)
{
    __shared__ unsigned short sF[4][16*72];
    __shared__ unsigned short sQ[4][16*72];
    __shared__ unsigned short sK[4][16*72];
    __shared__ float sSeg[64];

    int t = threadIdx.x, w = t >> 6, l = t & 63;
    int lc = l & 15, lg = l >> 4;
    int rblk = blockIdx.x * 64;
    int r0 = rblk + w * 16;
    int o0 = offs[0], o1 = offs[1], o2 = offs[2];
    bool fast = seg_of(rblk, o0,o1,o2) == seg_of(rblk + 63, o0,o1,o2);

    if (t < 64) sSeg[t] = 0.f;
    __syncthreads();

    stage_rows_f32(feat + (size_t)r0*64, sF[w], l);
    short8 a0 = *(const short8*)(sF[w] + lc*72 + lg*8);
    short8 a1 = *(const short8*)(sF[w] + lc*72 + 32 + lg*8);

    float bqc[4], bkc[4], bvc[4];
    #pragma unroll
    for (int ct = 0; ct < 4; ++ct) {
        bqc[ct] = biasqF[ct*16 + lc];
        bkc[ct] = biaskF[ct*16 + lc];
        bvc[ct] = bv[ct*16 + lc];
    }

    // ---- q ----
    #pragma unroll
    for (int ct = 0; ct < 4; ++ct) {
        f32x4 z = {0.f,0.f,0.f,0.f};
        short8 b0 = *(const short8*)(WqF + (ct*2+0)*512 + l*8);
        short8 b1 = *(const short8*)(WqF + (ct*2+1)*512 + l*8);
        f32x4 c = __builtin_amdgcn_mfma_f32_16x16x32_bf16(a0, b0, z, 0,0,0);
        c = __builtin_amdgcn_mfma_f32_16x16x32_bf16(a1, b1, c, 0,0,0);
        float cmax = 0.f;
        #pragma unroll
        for (int reg = 0; reg < 4; ++reg) {
            float qv = fmaxf(c[reg] + bqc[ct], 0.f);
            sQ[w][(lg*4 + reg)*72 + ct*16 + lc] = f2bf(qv);
            if (fast) cmax = fmaxf(cmax, qv);
            else atomicMax((unsigned int*)&seg_max[seg_of(r0 + lg*4 + reg,o0,o1,o2)*64 + ct*16 + lc],
                           __float_as_uint(qv));
        }
        if (fast) {
            cmax = fmaxf(cmax, __shfl_xor(cmax, 16));
            cmax = fmaxf(cmax, __shfl_xor(cmax, 32));
            if (lg == 0)
                atomicMax((unsigned int*)&sSeg[ct*16 + lc], __float_as_uint(cmax));
        }
    }
    // ---- seg-max combine early ----
    __syncthreads();
    if (fast && t < 64)
        atomicMax((unsigned int*)&seg_max[seg_of(rblk,o0,o1,o2)*64 + t],
                  __float_as_uint(sSeg[t]));

    // ---- k ----
    #pragma unroll
    for (int ct = 0; ct < 4; ++ct) {
        f32x4 z = {0.f,0.f,0.f,0.f};
        short8 b0 = *(const short8*)(WkF + (ct*2+0)*512 + l*8);
        short8 b1 = *(const short8*)(WkF + (ct*2+1)*512 + l*8);
        f32x4 c = __builtin_amdgcn_mfma_f32_16x16x32_bf16(a0, b0, z, 0,0,0);
        c = __builtin_amdgcn_mfma_f32_16x16x32_bf16(a1, b1, c, 0,0,0);
        #pragma unroll
        for (int reg = 0; reg < 4; ++reg)
            sK[w][(lg*4 + reg)*72 + ct*16 + lc] = f2bf(fmaxf(c[reg] + bkc[ct], 0.f));
    }
    // ---- v (staged bf16 into sF, which is dead now) ----
    #pragma unroll
    for (int ct = 0; ct < 4; ++ct) {
        f32x4 z = {0.f,0.f,0.f,0.f};
        short8 b0 = *(const short8*)(WvF + (ct*2+0)*512 + l*8);
        short8 b1 = *(const short8*)(WvF + (ct*2+1)*512 + l*8);
        f32x4 c = __builtin_amdgcn_mfma_f32_16x16x32_bf16(a0, b0, z, 0,0,0);
        c = __builtin_amdgcn_mfma_f32_16x16x32_bf16(a1, b1, c, 0,0,0);
        #pragma unroll
        for (int reg = 0; reg < 4; ++reg)
            sF[w][(lg*4 + reg)*72 + ct*16 + lc] = f2bf(c[reg] + bvc[ct]);
    }
    // ---- kw / qw via MFMA (K=64 -> 8 cols) ----
    {
        short8 wb0 = *(const short8*)(weW1F + l*8);
        short8 wb1 = *(const short8*)(weW1F + 512 + l*8);
        short8 aq0 = *(const short8*)(sQ[w] + lc*72 + lg*8);
        short8 aq1 = *(const short8*)(sQ[w] + lc*72 + 32 + lg*8);
        short8 ak0 = *(const short8*)(sK[w] + lc*72 + lg*8);
        short8 ak1 = *(const short8*)(sK[w] + lc*72 + 32 + lg*8);
        f32x4 z = {0.f,0.f,0.f,0.f};
        f32x4 cq = __builtin_amdgcn_mfma_f32_16x16x32_bf16(aq0, wb0, z, 0,0,0);
        cq = __builtin_amdgcn_mfma_f32_16x16x32_bf16(aq1, wb1, cq, 0,0,0);
        f32x4 ck = __builtin_amdgcn_mfma_f32_16x16x32_bf16(ak0, wb0, z, 0,0,0);
        ck = __builtin_amdgcn_mfma_f32_16x16x32_bf16(ak1, wb1, ck, 0,0,0);
        if (lc < 8) {
            #pragma unroll
            for (int reg = 0; reg < 4; ++reg) {
                qw[(size_t)(r0 + lg*4 + reg)*8 + lc] = cq[reg];
                kw[(size_t)(r0 + lg*4 + reg)*8 + lc] = ck[reg];
            }
        }
    }
    // ---- q_bf / v_bf global writes ----
    #pragma unroll
    for (int rep = 0; rep < 2; ++rep) {
        int row = (l >> 3) + rep*8;
        int ch = (l & 7) * 8;
        short8 vq = *(const short8*)(sQ[w] + row*72 + ch);
        *(short8*)(q_bf + (size_t)(r0 + row)*64 + ch) = vq;
        short8 vv = *(const short8*)(sF[w] + row*72 + ch);
        *(short8*)(v_bf + (size_t)(r0 + row)*64 + ch) = vv;
    }
}

// ---------------------------------------------------------------------------
// K3 (fused): gate (phase A, incl. per-block gseg2) + PE/softmax/einsum.
// LDS 24.1 KB -> 6 blocks/CU. xe computed lazily in rt loop (no xr[16] held).
// ---------------------------------------------------------------------------
__global__ __launch_bounds__(256, 6) void k_main(
    const float* __restrict__ coord, const int* __restrict__ ridx,
    const unsigned short* __restrict__ v_bf, const unsigned short* __restrict__ q_bf,
    const float* __restrict__ kw, const float* __restrict__ qw,
    const float* __restrict__ peb1f, const float* __restrict__ cvecg,
    const float* __restrict__ we_b2, const float* __restrict__ cg_b2,
    const float* __restrict__ seg_max, const float* __restrict__ cgW1cF,
    const float* __restrict__ cgb1f, const int* __restrict__ offs,
    const unsigned short* __restrict__ W1frag, const unsigned short* __restrict__ Wcfrag,
    const unsigned short* __restrict__ W2frag,
    const unsigned short* __restrict__ cgW1aF, const unsigned short* __restrict__ cgW1bF,
    const unsigned short* __restrict__ cgW2F,
    float* __restrict__ out)
{
    __shared__ __align__(16) unsigned short sXe[4*640];    // 5120 B per-rt xe staging
    __shared__ __align__(16) unsigned short sA2[4][16*72]; // 9216 B per-wave H1
    __shared__ __align__(16) unsigned short sU[3584];      // 7168 B union
    __shared__ float sGate[16][9];                         // 576 B
    __shared__ float sGseg[4][64];                         // 1024 B
    __shared__ int sIds[256];                              // 1024 B

    int t = threadIdx.x, w = t >> 6, l = t & 63;
    int lc = l & 15, lg = l >> 4;
    int n0 = blockIdx.x * 16;
    int o0 = offs[0], o1 = offs[1], o2 = offs[2];

    unsigned short* sQg = sU;
    unsigned short* sN  = sU + 1152;
    unsigned short* sHg = sU + 2304;
    unsigned short* sAh2w  = sU + w*128;
    unsigned short* sAttnB = sU + 512;

    // ---- step 1: ids + delta (3 regs held; trig deferred) + gseg2 ----
    int id = ridx[(size_t)n0*16 + t];
    sIds[t] = id;
    int ids = max(id, 0);
    int nself = n0 + (t >> 4);
    float dx, dy, dz;
    {
        float cx = coord[nself*3], cy = coord[nself*3+1], cz = coord[nself*3+2];
        dx = coord[ids*3]   - cx;
        dy = coord[ids*3+1] - cy;
        dz = coord[ids*3+2] - cz;
    }
    if (t < 64) stage_rows_bf16(q_bf + (size_t)n0*64, sQg, t);
    // gseg2 per block: thread (s=w, c=l)
    {
        float a = cgb1f[l];
        #pragma unroll 8
        for (int j = 0; j < 64; ++j)
            a += seg_max[w*64 + j] * cgW1cF[j*64 + l];
        sGseg[w][l] = a;
    }
    __syncthreads();   // sIds + sQg + sGseg ready

    // ---- step 2: neighbor-max gather (lane = point p, col-slice s) ----
    {
        int p = t >> 4, s = t & 15;
        const int* ip = &sIds[p*16];
        float m0 = 0.f, m1 = 0.f, m2 = 0.f, m3 = 0.f;
        #pragma unroll
        for (int kb = 0; kb < 16; kb += 4) {
            uint2 u[4];
            #pragma unroll
            for (int j = 0; j < 4; ++j) {
                int idn = max(ip[kb + j], 0);
                u[j] = *(const uint2*)(q_bf + (size_t)idn*64 + s*4);
            }
            #pragma unroll
            for (int j = 0; j < 4; ++j) {
                m0 = fmaxf(m0, bflo(u[j].x)); m1 = fmaxf(m1, bfhi(u[j].x));
                m2 = fmaxf(m2, bflo(u[j].y)); m3 = fmaxf(m3, bfhi(u[j].y));
            }
        }
        unsigned int* d = (unsigned int*)(sN + p*72 + s*4);
        d[0] = pack2bf(m0, m1);
        d[1] = pack2bf(m2, m3);
    }
    __syncthreads();   // sN ready

    // ---- step 3: gate H1 (wave w owns output col-tile ct=w) ----
    {
        short8 a0 = *(const short8*)(sQg + lc*72 + lg*8);
        short8 a1 = *(const short8*)(sQg + lc*72 + 32 + lg*8);
        short8 nv0 = *(const short8*)(sN + lc*72 + lg*8);
        short8 nv1 = *(const short8*)(sN + lc*72 + 32 + lg*8);
        f32x4 c4;
        #pragma unroll
        for (int reg = 0; reg < 4; ++reg)
            c4[reg] = sGseg[seg_of(n0 + lg*4 + reg, o0, o1, o2)][w*16 + lc];
        short8 b0 = *(const short8*)(cgW1aF + (w*2+0)*512 + l*8);
        short8 b1 = *(const short8*)(cgW1aF + (w*2+1)*512 + l*8);
        c4 = __builtin_amdgcn_mfma_f32_16x16x32_bf16(a0, b0, c4, 0,0,0);
        c4 = __builtin_amdgcn_mfma_f32_16x16x32_bf16(a1, b1, c4, 0,0,0);
        short8 b2 = *(const short8*)(cgW1bF + (w*2+0)*512 + l*8);
        short8 b3 = *(const short8*)(cgW1bF + (w*2+1)*512 + l*8);
        c4 = __builtin_amdgcn_mfma_f32_16x16x32_bf16(nv0, b2, c4, 0,0,0);
        c4 = __builtin_amdgcn_mfma_f32_16x16x32_bf16(nv1, b3, c4, 0,0,0);
        #pragma unroll
        for (int reg = 0; reg < 4; ++reg)
            sHg[(lg*4 + reg)*72 + w*16 + lc] = f2bf(fmaxf(c4[reg], 0.f));
    }
    __syncthreads();   // sHg ready

    // ---- step 4: final gate MFMA (wave 0 only) ----
    if (w == 0) {
        short8 ah0 = *(const short8*)(sHg + lc*72 + lg*8);
        short8 ah1 = *(const short8*)(sHg + lc*72 + 32 + lg*8);
        short8 w0f = *(const short8*)(cgW2F + l*8);
        short8 w1f = *(const short8*)(cgW2F + 512 + l*8);
        float bg = cg_b2[lc & 7];
        f32x4 cg;
        #pragma unroll
        for (int reg = 0; reg < 4; ++reg) cg[reg] = bg;
        cg = __builtin_amdgcn_mfma_f32_16x16x32_bf16(ah0, w0f, cg, 0,0,0);
        cg = __builtin_amdgcn_mfma_f32_16x16x32_bf16(ah1, w1f, cg, 0,0,0);
        if (lc < 8) {
            #pragma unroll
            for (int reg = 0; reg < 4; ++reg)
                sGate[lg*4 + reg][lc] = 1.f / (1.f + __expf(-cg[reg]));
        }
    }
    __syncthreads();   // sGate ready; phase-A scratch dead -> reuse

    // ---- phase B: per-wave PE pipeline ----
    int g7 = lc & 7;
    short8 bW1[4], bWc[2], bW2;
    #pragma unroll
    for (int ct = 0; ct < 4; ++ct) bW1[ct] = *(const short8*)(W1frag + ct*512 + l*8);
    bWc[0] = *(const short8*)(Wcfrag + l*8);
    bWc[1] = *(const short8*)(Wcfrag + 512 + l*8);
    bW2 = *(const short8*)(W2frag + l*8);

    float bias1[4];
    #pragma unroll
    for (int ct = 0; ct < 4; ++ct) bias1[ct] = peb1f[16*ct + lc];
    float cvec_g = cvecg[g7];
    float bias3 = we_b2[g7];
    unsigned short* sXw = sXe + w*640;

    #pragma unroll
    for (int rt = 0; rt < 4; ++rt) {
        int n = n0 + w*4 + rt;
        // lazily compute + stage this tile's xe rows (lanes lg==rt own them);
        // all trig temporaries die inside the if -> no held registers.
        if (lg == rt) {
            unsigned int* dst = (unsigned int*)(sXw + lc*40);
            float dist = sqrtf(dx*dx + dy*dy + dz*dz);
            dst[0] = pack2bf(dx, dy);
            dst[1] = pack2bf(dz, dist);
            float sx, cx2, sy, cy2, sz, cz2;
            __sincosf(dx * 3.14159265358979f, &sx, &cx2);
            __sincosf(dy * 3.14159265358979f, &sy, &cy2);
            __sincosf(dz * 3.14159265358979f, &sz, &cz2);
            dst[2]  = pack2bf(sx, sy);
            dst[3]  = pack2bf(cx2, cy2);
            dst[10] = pack2bf(sz, cz2);
            #pragma unroll
            for (int fi = 1; fi < 4; ++fi) {
                float nsx = 2.f*sx*cx2, ncx = fmaf(-2.f*sx, sx, 1.f);
                float nsy = 2.f*sy*cy2, ncy = fmaf(-2.f*sy, sy, 1.f);
                float nsz = 2.f*sz*cz2, ncz = fmaf(-2.f*sz, sz, 1.f);
                dst[2 + 2*fi] = pack2bf(nsx, nsy);
                dst[3 + 2*fi] = pack2bf(ncx, ncy);
                dst[10 + fi]  = pack2bf(nsz, ncz);
                sx = nsx; cx2 = ncx; sy = nsy; cy2 = ncy; sz = nsz; cz2 = ncz;
            }
            dst[14] = 0u; dst[15] = 0u;
        }
        short8 a1 = *(const short8*)(sXw + lc*40 + lg*8);
        f32x4 c1[4];
        #pragma unroll
        for (int ct = 0; ct < 4; ++ct) {
            f32x4 z = {0.f, 0.f, 0.f, 0.f};
            c1[ct] = __builtin_amdgcn_mfma_f32_16x16x32_bf16(a1, bW1[ct], z, 0, 0, 0);
        }
        #pragma unroll
        for (int ct = 0; ct < 4; ++ct) {
            #pragma unroll
            for (int reg = 0; reg < 4; ++reg) {
                float h1 = fmaxf(c1[ct][reg] + bias1[ct], 0.f);
                sA2[w][(lg*4 + reg)*72 + 16*ct + lc] = f2bf(h1);
            }
        }
        int ids_r[4];
        #pragma unroll
        for (int reg = 0; reg < 4; ++reg) ids_r[reg] = sIds[w*64 + rt*16 + lg*4 + reg];
        float qwv = qw[(size_t)n*8 + g7];
        f32x4 c2;
        #pragma unroll
        for (int reg = 0; reg < 4; ++reg)
            c2[reg] = kw[(size_t)max(ids_r[reg],0)*8 + g7] - qwv + cvec_g;
        short8 a20 = *(const short8*)(sA2[w] + lc*72 + lg*8);
        short8 a21 = *(const short8*)(sA2[w] + lc*72 + 32 + lg*8);
        c2 = __builtin_amdgcn_mfma_f32_16x16x32_bf16(a20, bWc[0], c2, 0, 0, 0);
        c2 = __builtin_amdgcn_mfma_f32_16x16x32_bf16(a21, bWc[1], c2, 0, 0, 0);
        if (lc < 8) {
            #pragma unroll
            for (int reg = 0; reg < 4; ++reg)
                sAh2w[(lg*4 + reg)*8 + lc] = f2bf(fmaxf(c2[reg], 0.f));
        }
        short8 a3 = {0,0,0,0,0,0,0,0};
        if (l < 16) a3 = *(const short8*)(sAh2w + lc*8);
        f32x4 c3;
        #pragma unroll
        for (int reg = 0; reg < 4; ++reg) c3[reg] = bias3;
        c3 = __builtin_amdgcn_mfma_f32_16x16x32_bf16(a3, bW2, c3, 0, 0, 0);
        float gv = sGate[w*4 + rt][g7];
        float lgt[4];
        #pragma unroll
        for (int reg = 0; reg < 4; ++reg) lgt[reg] = c3[reg] * gv;
        float m = fmaxf(fmaxf(lgt[0], lgt[1]), fmaxf(lgt[2], lgt[3]));
        m = fmaxf(m, __shfl_xor(m, 16));
        m = fmaxf(m, __shfl_xor(m, 32));
        float e[4], s = 0.f;
        #pragma unroll
        for (int reg = 0; reg < 4; ++reg) { e[reg] = __expf(lgt[reg] - m); s += e[reg]; }
        s += __shfl_xor(s, 16);
        s += __shfl_xor(s, 32);
        float inv = 1.f / s;
        if (lc < 8) {
            float av[4];
            #pragma unroll
            for (int reg = 0; reg < 4; ++reg) {
                int idv = ids_r[reg];
                float mf = (idv >= 0) ? 1.f : ((idv == -1) ? 0.f : -1.f);
                av[reg] = e[reg] * inv * mf;
            }
            // layout [point][gh=lc][k2=lg*4+reg], stride 24
            unsigned int* d = (unsigned int*)(sAttnB + ((w*4 + rt)*8 + lc)*24 + lg*4);
            d[0] = pack2bf(av[0], av[1]);
            d[1] = pack2bf(av[2], av[3]);
        }
    }

    // ---- einsum: attn via 2x b128, late v-gather ----
    {
        int p = lg, kk = lc;
        int n2 = n0 + w*4 + p;
        const unsigned short* ab = sAttnB + ((w*4 + p)*8 + (kk >> 1))*24;
        short8 aa0 = *(const short8*)(ab);
        short8 aa1 = *(const short8*)(ab + 8);
        float4 o = make_float4(0.f, 0.f, 0.f, 0.f);
        #pragma unroll
        for (int k2 = 0; k2 < 16; ++k2) {
            int id2 = max(sIds[w*64 + p*16 + k2], 0);
            unsigned short ar = (k2 < 8) ? (unsigned short)aa0[k2] : (unsigned short)aa1[k2-8];
            float a = bflo((unsigned int)ar);
            uint2 u = *(const uint2*)(v_bf + (size_t)id2*64 + kk*4);
            o.x += a * bflo(u.x); o.y += a * bfhi(u.x);
            o.z += a * bflo(u.y); o.w += a * bfhi(u.y);
        }
        *(float4*)(out + (size_t)n2*64 + kk*4) = o;
    }
}

// ---------------------------------------------------------------------------
extern "C" void kernel_launch(void* const* d_in, const int* in_sizes, int n_in,
                              void* d_out, int out_size, void* d_ws, size_t ws_size,
                              hipStream_t stream)
{
    const float* feat  = (const float*)d_in[0];
    const float* coord = (const float*)d_in[1];
    const int*   ridx  = (const int*)d_in[2];
    const int*   offs  = (const int*)d_in[3];
    const float* Wq = (const float*)d_in[4];  const float* bq = (const float*)d_in[5];  const float* bnq = (const float*)d_in[6];
    const float* Wk = (const float*)d_in[7];  const float* bk = (const float*)d_in[8];  const float* bnk = (const float*)d_in[9];
    const float* Wv = (const float*)d_in[10]; const float* bv = (const float*)d_in[11];
    const float* pe_W1 = (const float*)d_in[12]; const float* pe_b1 = (const float*)d_in[13]; const float* pe_bn = (const float*)d_in[14];
    const float* pe_W2 = (const float*)d_in[15]; const float* pe_b2 = (const float*)d_in[16];
    const float* we_W1 = (const float*)d_in[17]; const float* we_b1 = (const float*)d_in[18]; const float* we_bn = (const float*)d_in[19];
    const float* we_W2 = (const float*)d_in[20]; const float* we_b2 = (const float*)d_in[21];
    const float* cg_W1 = (const float*)d_in[22]; const float* cg_b1 = (const float*)d_in[23]; const float* cg_bn = (const float*)d_in[24];
    const float* cg_W2 = (const float*)d_in[25]; const float* cg_b2 = (const float*)d_in[26];
    float* out = (float*)d_out;
    int N = in_sizes[0] / 64;

    // bf16 tables first (16B aligned at ws base)
    unsigned short* v_bf = (unsigned short*)d_ws;               // N*64
    unsigned short* q_bf = v_bf + (size_t)N*64;                 // N*64
    float* kwp   = (float*)(q_bf + (size_t)N*64);               // N*8
    float* qwp   = kwp + (size_t)N*8;                           // N*8
    float* segm  = qwp + (size_t)N*8;                           // 256
    float* peb1f = segm + 256;                                  // 64
    float* cvecg = peb1f + 64;                                  // 8
    float* cgb1f = cvecg + 8;                                   // 64
    float* biasqF= cgb1f + 64;                                  // 64
    float* biaskF= biasqF + 64;                                 // 64
    float* pad0  = biaskF + 64;                                 // 56 pad
    float* cgW1cF= pad0 + 56;                                   // 4096
    unsigned short* WqF     = (unsigned short*)(cgW1cF + 4096); // 4096
    unsigned short* WkF     = WqF + 4096;                       // 4096
    unsigned short* WvF     = WkF + 4096;                       // 4096
    unsigned short* weW1F   = WvF + 4096;                       // 1024
    unsigned short* cgW1aF  = weW1F + 1024;                     // 4096
    unsigned short* cgW1bF  = cgW1aF + 4096;                    // 4096
    unsigned short* cgW2F   = cgW1bF + 4096;                    // 1024
    unsigned short* W1frag  = cgW2F + 1024;                     // 2048
    unsigned short* Wcfrag  = W1frag + 2048;                    // 1024
    unsigned short* W2frag  = Wcfrag + 1024;                    // 512

    k_prep<<<1, 256, 0, stream>>>(pe_W1, pe_b1, pe_bn, pe_W2, pe_b2,
                                  we_W1, we_b1, we_bn, we_W2,
                                  cg_W1, cg_b1, cg_bn, cg_W2,
                                  Wq, bq, bnq, Wk, bk, bnk, Wv,
                                  peb1f, cvecg, cgb1f, biasqF, biaskF, cgW1cF, segm,
                                  WqF, WkF, WvF, weW1F, cgW1aF, cgW1bF, cgW2F,
                                  W1frag, Wcfrag, W2frag);
    k_qkv<<<N/64, 256, 0, stream>>>(feat, offs, WqF, WkF, WvF, weW1F,
                                    biasqF, biaskF, bv,
                                    v_bf, q_bf, kwp, qwp, segm);
    k_main<<<N/16, 256, 0, stream>>>(coord, ridx, v_bf, q_bf, kwp, qwp,
                                     peb1f, cvecg, we_b2, cg_b2,
                                     segm, cgW1cF, cgb1f, offs,
                                     W1frag, Wcfrag, W2frag,
                                     cgW1aF, cgW1bF, cgW2F, out);
}

// Round 13
// 106.240 us; speedup vs baseline: 1.2729x; 1.2615x over previous
//
#include <hip/hip_runtime.h>
#include <hip/hip_bf16.h>

#define EPSF 1e-5f

typedef __attribute__((ext_vector_type(8))) short short8;
typedef __attribute__((ext_vector_type(4))) float f32x4;

__device__ __forceinline__ int seg_of(int i, int o0, int o1, int o2) {
    return (i >= o0) + (i >= o1) + (i >= o2);
}

__device__ __forceinline__ unsigned short f2bf(float f) {
    unsigned int u = __float_as_uint(f);
    unsigned int r = (u + 0x7fffu + ((u >> 16) & 1u)) >> 16;
    return (unsigned short)r;
}
__device__ __forceinline__ unsigned int pack2bf(float a, float b) {
    return (unsigned int)f2bf(a) | ((unsigned int)f2bf(b) << 16);
}
__device__ __forceinline__ float bflo(unsigned int u) { return __uint_as_float(u << 16); }
__device__ __forceinline__ float bfhi(unsigned int u) { return __uint_as_float(u & 0xffff0000u); }

// stage 16 rows x 64 bf16 from global (row-major 64) into LDS (stride 72)
__device__ __forceinline__ void stage_rows_bf16(const unsigned short* __restrict__ src,
                                                unsigned short* dst, int l) {
    int row = l >> 2, cq = (l & 3) * 16;
    const short8* s = (const short8*)(src + (size_t)row*64 + cq);
    short8* d0 = (short8*)(dst + row*72 + cq);
    d0[0] = s[0];
    d0[1] = s[1];
}

// stage 16 rows x 64 f32 from global into bf16 LDS (stride 72)
__device__ __forceinline__ void stage_rows_f32(const float* __restrict__ src,
                                               unsigned short* dst, int l) {
    int row = l >> 2, cq = (l & 3) * 16;
    const float4* s = (const float4*)(src + (size_t)row*64 + cq);
    unsigned int* d = (unsigned int*)(dst + row*72 + cq);
    #pragma unroll
    for (int i = 0; i < 4; ++i) {
        float4 f = s[i];
        d[i*2]   = pack2bf(f.x, f.y);
        d[i*2+1] = pack2bf(f.z, f.w);
    }
}

// ---------------------------------------------------------------------------
// K0: fold BNs; build all bf16 B-fragments + folded biases; zero seg_max.
// ---------------------------------------------------------------------------
__global__ __launch_bounds__(256) void k_prep(
    const float* __restrict__ pe_W1, const float* __restrict__ pe_b1, const float* __restrict__ pe_bn,
    const float* __restrict__ pe_W2, const float* __restrict__ pe_b2,
    const float* __restrict__ we_W1, const float* __restrict__ we_b1, const float* __restrict__ we_bn,
    const float* __restrict__ we_W2,
    const float* __restrict__ cg_W1, const float* __restrict__ cg_b1, const float* __restrict__ cg_bn,
    const float* __restrict__ cg_W2,
    const float* __restrict__ Wq, const float* __restrict__ bq, const float* __restrict__ bnq,
    const float* __restrict__ Wk, const float* __restrict__ bk, const float* __restrict__ bnk,
    const float* __restrict__ Wv,
    float* __restrict__ peb1f, float* __restrict__ cvecg, float* __restrict__ cgb1f,
    float* __restrict__ biasqF, float* __restrict__ biaskF, float* __restrict__ cgW1cF,
    float* __restrict__ segm,
    unsigned short* __restrict__ WqF, unsigned short* __restrict__ WkF, unsigned short* __restrict__ WvF,
    unsigned short* __restrict__ weW1F, unsigned short* __restrict__ cgW1aF,
    unsigned short* __restrict__ cgW1bF, unsigned short* __restrict__ cgW2F,
    unsigned short* __restrict__ W1frag, unsigned short* __restrict__ Wcfrag,
    unsigned short* __restrict__ W2frag)
{
    int t = threadIdx.x;
    __shared__ float sc1[64], csc[64], sqv[64], skv[64], wsc[8], wsh[8];
    __shared__ float sWe[64][8], sWb[8], sWc[64][8];
    segm[t] = 0.f;
    if (t < 64) {
        float g = pe_bn[t], b = pe_bn[64+t], m = pe_bn[128+t], v = pe_bn[192+t];
        float s = g / sqrtf(v + EPSF);
        sc1[t] = s; peb1f[t] = pe_b1[t]*s + (b - m*s);
        g = cg_bn[t]; b = cg_bn[64+t]; m = cg_bn[128+t]; v = cg_bn[192+t];
        s = g / sqrtf(v + EPSF);
        csc[t] = s; cgb1f[t] = cg_b1[t]*s + (b - m*s);
        g = bnq[t]; b = bnq[64+t]; m = bnq[128+t]; v = bnq[192+t];
        s = g / sqrtf(v + EPSF);
        sqv[t] = s; biasqF[t] = bq[t]*s + (b - m*s);
        g = bnk[t]; b = bnk[64+t]; m = bnk[128+t]; v = bnk[192+t];
        s = g / sqrtf(v + EPSF);
        skv[t] = s; biaskF[t] = bk[t]*s + (b - m*s);
    }
    if (t < 8) {
        float g = we_bn[t], b = we_bn[8+t], m = we_bn[16+t], v = we_bn[24+t];
        float s = g / sqrtf(v + EPSF);
        wsc[t] = s; wsh[t] = b - m*s;
    }
    __syncthreads();
    for (int u = t; u < 512; u += 256) { int g = u & 7; sWe[u >> 3][g] = we_W1[u] * wsc[g]; }
    if (t < 8) sWb[t] = we_b1[t] * wsc[t] + wsh[t];
    __syncthreads();
    for (int u = t; u < 512; u += 256) {
        int h = u >> 3, g = u & 7;
        float a = 0.f;
        for (int c = 0; c < 64; ++c) a += pe_W2[h*64 + c] * sWe[c][g];
        sWc[h][g] = a;
    }
    if (t < 8) {
        float a = sWb[t];
        for (int c = 0; c < 64; ++c) a += pe_b2[c] * sWe[c][t];
        cvecg[t] = a;
    }
    __syncthreads();
    // 64x64 frags (8 tiles x 512)
    for (int u = t; u < 4096; u += 256) {
        int tile = u >> 9, l = (u >> 3) & 63, j = u & 7;
        int col = (tile >> 1)*16 + (l & 15);
        int kk  = (tile & 1)*32 + (l >> 4)*8 + j;
        WqF[u]    = f2bf(Wq[kk*64 + col] * sqv[col]);
        WkF[u]    = f2bf(Wk[kk*64 + col] * skv[col]);
        WvF[u]    = f2bf(Wv[kk*64 + col]);
        cgW1aF[u] = f2bf(cg_W1[kk*64 + col] * csc[col]);
        cgW1bF[u] = f2bf(cg_W1[(64 + kk)*64 + col] * csc[col]);
    }
    // 64->8/8->8 frags (2 tiles, cols padded to 16)
    for (int u = t; u < 1024; u += 256) {
        int tile = u >> 9, l = (u >> 3) & 63, j = u & 7;
        int col = l & 15;
        int kk  = tile*32 + (l >> 4)*8 + j;
        weW1F[u] = (col < 8) ? f2bf(sWe[kk][col]) : 0;
        cgW2F[u] = (col < 8) ? f2bf(cg_W2[kk*8 + col]) : 0;
    }
    // cgW1cF: rows 128..191 of cg_W1, BN-folded, f32
    for (int u = t; u < 4096; u += 256) {
        int k = u >> 6, c = u & 63;
        cgW1cF[u] = cg_W1[(128 + k)*64 + c] * csc[c];
    }
    // k_main frags
    {
        int ct = t >> 6, l = t & 63;
        int col = 16*ct + (l & 15), kg = l >> 4;
        #pragma unroll
        for (int j = 0; j < 8; ++j) {
            int k = kg*8 + j;
            float v = (k < 28) ? pe_W1[k*64 + col] * sc1[col] : 0.f;
            W1frag[ct*512 + l*8 + j] = f2bf(v);
        }
    }
    if (t < 128) {
        int kg = t >> 6, l = t & 63, g = l & 15;
        #pragma unroll
        for (int j = 0; j < 8; ++j) {
            int k = kg*32 + (l >> 4)*8 + j;
            float v = (g < 8) ? sWc[k][g] : 0.f;
            Wcfrag[kg*512 + l*8 + j] = f2bf(v);
        }
    }
    if (t < 64) {
        int l = t, g = l & 15;
        #pragma unroll
        for (int j = 0; j < 8; ++j) {
            float v = (l < 16 && g < 8) ? we_W2[j*8 + g] : 0.f;
            W2frag[l*8 + j] = f2bf(v);
        }
    }
}

// ---------------------------------------------------------------------------
// K1: MFMA q/k/v. Block = 4 waves x 16 rows = 64 rows, wave-private LDS.
// ---------------------------------------------------------------------------
__global__ __launch_bounds__(256) void k_qkv(
    const float* __restrict__ feat, const int* __restrict__ offs,
    const unsigned short* __restrict__ WqF, const unsigned short* __restrict__ WkF,
    const unsigned short* __restrict__ WvF, const unsigned short* __restrict__ weW1F,
    const float* __restrict__ biasqF, const float* __restrict__ biaskF,
    const float* __restrict__ bv,
    unsigned short* __restrict__ v_bf, unsigned short* __restrict__ q_bf,
    float* __restrict__ kw, float* __restrict__ qw, float* __restrict__ seg_max)
{
    __shared__ unsigned short sF[4][16*72];
    __shared__ unsigned short sQ[4][16*72];
    __shared__ unsigned short sK[4][16*72];
    __shared__ float sSeg[64];

    int t = threadIdx.x, w = t >> 6, l = t & 63;
    int lc = l & 15, lg = l >> 4;
    int rblk = blockIdx.x * 64;
    int r0 = rblk + w * 16;
    int o0 = offs[0], o1 = offs[1], o2 = offs[2];
    bool fast = seg_of(rblk, o0,o1,o2) == seg_of(rblk + 63, o0,o1,o2);

    if (t < 64) sSeg[t] = 0.f;
    __syncthreads();

    stage_rows_f32(feat + (size_t)r0*64, sF[w], l);
    short8 a0 = *(const short8*)(sF[w] + lc*72 + lg*8);
    short8 a1 = *(const short8*)(sF[w] + lc*72 + 32 + lg*8);

    float bqc[4], bkc[4], bvc[4];
    #pragma unroll
    for (int ct = 0; ct < 4; ++ct) {
        bqc[ct] = biasqF[ct*16 + lc];
        bkc[ct] = biaskF[ct*16 + lc];
        bvc[ct] = bv[ct*16 + lc];
    }

    // ---- q ----
    #pragma unroll
    for (int ct = 0; ct < 4; ++ct) {
        f32x4 z = {0.f,0.f,0.f,0.f};
        short8 b0 = *(const short8*)(WqF + (ct*2+0)*512 + l*8);
        short8 b1 = *(const short8*)(WqF + (ct*2+1)*512 + l*8);
        f32x4 c = __builtin_amdgcn_mfma_f32_16x16x32_bf16(a0, b0, z, 0,0,0);
        c = __builtin_amdgcn_mfma_f32_16x16x32_bf16(a1, b1, c, 0,0,0);
        float cmax = 0.f;
        #pragma unroll
        for (int reg = 0; reg < 4; ++reg) {
            float qv = fmaxf(c[reg] + bqc[ct], 0.f);
            sQ[w][(lg*4 + reg)*72 + ct*16 + lc] = f2bf(qv);
            if (fast) cmax = fmaxf(cmax, qv);
            else atomicMax((unsigned int*)&seg_max[seg_of(r0 + lg*4 + reg,o0,o1,o2)*64 + ct*16 + lc],
                           __float_as_uint(qv));
        }
        if (fast) {
            cmax = fmaxf(cmax, __shfl_xor(cmax, 16));
            cmax = fmaxf(cmax, __shfl_xor(cmax, 32));
            if (lg == 0)
                atomicMax((unsigned int*)&sSeg[ct*16 + lc], __float_as_uint(cmax));
        }
    }
    // ---- seg-max combine early ----
    __syncthreads();
    if (fast && t < 64)
        atomicMax((unsigned int*)&seg_max[seg_of(rblk,o0,o1,o2)*64 + t],
                  __float_as_uint(sSeg[t]));

    // ---- k ----
    #pragma unroll
    for (int ct = 0; ct < 4; ++ct) {
        f32x4 z = {0.f,0.f,0.f,0.f};
        short8 b0 = *(const short8*)(WkF + (ct*2+0)*512 + l*8);
        short8 b1 = *(const short8*)(WkF + (ct*2+1)*512 + l*8);
        f32x4 c = __builtin_amdgcn_mfma_f32_16x16x32_bf16(a0, b0, z, 0,0,0);
        c = __builtin_amdgcn_mfma_f32_16x16x32_bf16(a1, b1, c, 0,0,0);
        #pragma unroll
        for (int reg = 0; reg < 4; ++reg)
            sK[w][(lg*4 + reg)*72 + ct*16 + lc] = f2bf(fmaxf(c[reg] + bkc[ct], 0.f));
    }
    // ---- v (staged bf16 into sF, which is dead now) ----
    #pragma unroll
    for (int ct = 0; ct < 4; ++ct) {
        f32x4 z = {0.f,0.f,0.f,0.f};
        short8 b0 = *(const short8*)(WvF + (ct*2+0)*512 + l*8);
        short8 b1 = *(const short8*)(WvF + (ct*2+1)*512 + l*8);
        f32x4 c = __builtin_amdgcn_mfma_f32_16x16x32_bf16(a0, b0, z, 0,0,0);
        c = __builtin_amdgcn_mfma_f32_16x16x32_bf16(a1, b1, c, 0,0,0);
        #pragma unroll
        for (int reg = 0; reg < 4; ++reg)
            sF[w][(lg*4 + reg)*72 + ct*16 + lc] = f2bf(c[reg] + bvc[ct]);
    }
    // ---- kw / qw via MFMA (K=64 -> 8 cols) ----
    {
        short8 wb0 = *(const short8*)(weW1F + l*8);
        short8 wb1 = *(const short8*)(weW1F + 512 + l*8);
        short8 aq0 = *(const short8*)(sQ[w] + lc*72 + lg*8);
        short8 aq1 = *(const short8*)(sQ[w] + lc*72 + 32 + lg*8);
        short8 ak0 = *(const short8*)(sK[w] + lc*72 + lg*8);
        short8 ak1 = *(const short8*)(sK[w] + lc*72 + 32 + lg*8);
        f32x4 z = {0.f,0.f,0.f,0.f};
        f32x4 cq = __builtin_amdgcn_mfma_f32_16x16x32_bf16(aq0, wb0, z, 0,0,0);
        cq = __builtin_amdgcn_mfma_f32_16x16x32_bf16(aq1, wb1, cq, 0,0,0);
        f32x4 ck = __builtin_amdgcn_mfma_f32_16x16x32_bf16(ak0, wb0, z, 0,0,0);
        ck = __builtin_amdgcn_mfma_f32_16x16x32_bf16(ak1, wb1, ck, 0,0,0);
        if (lc < 8) {
            #pragma unroll
            for (int reg = 0; reg < 4; ++reg) {
                qw[(size_t)(r0 + lg*4 + reg)*8 + lc] = cq[reg];
                kw[(size_t)(r0 + lg*4 + reg)*8 + lc] = ck[reg];
            }
        }
    }
    // ---- q_bf / v_bf global writes ----
    #pragma unroll
    for (int rep = 0; rep < 2; ++rep) {
        int row = (l >> 3) + rep*8;
        int ch = (l & 7) * 8;
        short8 vq = *(const short8*)(sQ[w] + row*72 + ch);
        *(short8*)(q_bf + (size_t)(r0 + row)*64 + ch) = vq;
        short8 vv = *(const short8*)(sF[w] + row*72 + ch);
        *(short8*)(v_bf + (size_t)(r0 + row)*64 + ch) = vv;
    }
}

// ---------------------------------------------------------------------------
// K3 (fused): gate (phase A, incl. per-block gseg2) + PE/softmax/einsum.
// LDS 24.1 KB; __launch_bounds__(256,5): VGPR cap ~102 (unified VGPR/AGPR)
// so no spill; 5 blocks/CU.
// ---------------------------------------------------------------------------
__global__ __launch_bounds__(256, 5) void k_main(
    const float* __restrict__ coord, const int* __restrict__ ridx,
    const unsigned short* __restrict__ v_bf, const unsigned short* __restrict__ q_bf,
    const float* __restrict__ kw, const float* __restrict__ qw,
    const float* __restrict__ peb1f, const float* __restrict__ cvecg,
    const float* __restrict__ we_b2, const float* __restrict__ cg_b2,
    const float* __restrict__ seg_max, const float* __restrict__ cgW1cF,
    const float* __restrict__ cgb1f, const int* __restrict__ offs,
    const unsigned short* __restrict__ W1frag, const unsigned short* __restrict__ Wcfrag,
    const unsigned short* __restrict__ W2frag,
    const unsigned short* __restrict__ cgW1aF, const unsigned short* __restrict__ cgW1bF,
    const unsigned short* __restrict__ cgW2F,
    float* __restrict__ out)
{
    __shared__ __align__(16) unsigned short sXe[4*640];    // 5120 B per-rt xe staging
    __shared__ __align__(16) unsigned short sA2[4][16*72]; // 9216 B per-wave H1
    __shared__ __align__(16) unsigned short sU[3584];      // 7168 B union
    __shared__ float sGate[16][9];                         // 576 B
    __shared__ float sGseg[4][64];                         // 1024 B
    __shared__ int sIds[256];                              // 1024 B

    int t = threadIdx.x, w = t >> 6, l = t & 63;
    int lc = l & 15, lg = l >> 4;
    int n0 = blockIdx.x * 16;
    int o0 = offs[0], o1 = offs[1], o2 = offs[2];

    unsigned short* sQg = sU;
    unsigned short* sN  = sU + 1152;
    unsigned short* sHg = sU + 2304;
    unsigned short* sAh2w  = sU + w*128;
    unsigned short* sAttnB = sU + 512;

    // ---- step 1: ids + delta (3 regs held; trig deferred) + gseg2 ----
    int id = ridx[(size_t)n0*16 + t];
    sIds[t] = id;
    int ids = max(id, 0);
    int nself = n0 + (t >> 4);
    float dx, dy, dz;
    {
        float cx = coord[nself*3], cy = coord[nself*3+1], cz = coord[nself*3+2];
        dx = coord[ids*3]   - cx;
        dy = coord[ids*3+1] - cy;
        dz = coord[ids*3+2] - cz;
    }
    if (t < 64) stage_rows_bf16(q_bf + (size_t)n0*64, sQg, t);
    // gseg2 per block: thread (s=w, c=l)
    {
        float a = cgb1f[l];
        #pragma unroll 8
        for (int j = 0; j < 64; ++j)
            a += seg_max[w*64 + j] * cgW1cF[j*64 + l];
        sGseg[w][l] = a;
    }
    __syncthreads();   // sIds + sQg + sGseg ready

    // ---- step 2: neighbor-max gather (lane = point p, col-slice s) ----
    {
        int p = t >> 4, s = t & 15;
        const int* ip = &sIds[p*16];
        float m0 = 0.f, m1 = 0.f, m2 = 0.f, m3 = 0.f;
        #pragma unroll
        for (int kb = 0; kb < 16; kb += 4) {
            uint2 u[4];
            #pragma unroll
            for (int j = 0; j < 4; ++j) {
                int idn = max(ip[kb + j], 0);
                u[j] = *(const uint2*)(q_bf + (size_t)idn*64 + s*4);
            }
            #pragma unroll
            for (int j = 0; j < 4; ++j) {
                m0 = fmaxf(m0, bflo(u[j].x)); m1 = fmaxf(m1, bfhi(u[j].x));
                m2 = fmaxf(m2, bflo(u[j].y)); m3 = fmaxf(m3, bfhi(u[j].y));
            }
        }
        unsigned int* d = (unsigned int*)(sN + p*72 + s*4);
        d[0] = pack2bf(m0, m1);
        d[1] = pack2bf(m2, m3);
    }
    __syncthreads();   // sN ready

    // ---- step 3: gate H1 (wave w owns output col-tile ct=w) ----
    {
        short8 a0 = *(const short8*)(sQg + lc*72 + lg*8);
        short8 a1 = *(const short8*)(sQg + lc*72 + 32 + lg*8);
        short8 nv0 = *(const short8*)(sN + lc*72 + lg*8);
        short8 nv1 = *(const short8*)(sN + lc*72 + 32 + lg*8);
        f32x4 c4;
        #pragma unroll
        for (int reg = 0; reg < 4; ++reg)
            c4[reg] = sGseg[seg_of(n0 + lg*4 + reg, o0, o1, o2)][w*16 + lc];
        short8 b0 = *(const short8*)(cgW1aF + (w*2+0)*512 + l*8);
        short8 b1 = *(const short8*)(cgW1aF + (w*2+1)*512 + l*8);
        c4 = __builtin_amdgcn_mfma_f32_16x16x32_bf16(a0, b0, c4, 0,0,0);
        c4 = __builtin_amdgcn_mfma_f32_16x16x32_bf16(a1, b1, c4, 0,0,0);
        short8 b2 = *(const short8*)(cgW1bF + (w*2+0)*512 + l*8);
        short8 b3 = *(const short8*)(cgW1bF + (w*2+1)*512 + l*8);
        c4 = __builtin_amdgcn_mfma_f32_16x16x32_bf16(nv0, b2, c4, 0,0,0);
        c4 = __builtin_amdgcn_mfma_f32_16x16x32_bf16(nv1, b3, c4, 0,0,0);
        #pragma unroll
        for (int reg = 0; reg < 4; ++reg)
            sHg[(lg*4 + reg)*72 + w*16 + lc] = f2bf(fmaxf(c4[reg], 0.f));
    }
    __syncthreads();   // sHg ready

    // ---- step 4: final gate MFMA (wave 0 only) ----
    if (w == 0) {
        short8 ah0 = *(const short8*)(sHg + lc*72 + lg*8);
        short8 ah1 = *(const short8*)(sHg + lc*72 + 32 + lg*8);
        short8 w0f = *(const short8*)(cgW2F + l*8);
        short8 w1f = *(const short8*)(cgW2F + 512 + l*8);
        float bg = cg_b2[lc & 7];
        f32x4 cg;
        #pragma unroll
        for (int reg = 0; reg < 4; ++reg) cg[reg] = bg;
        cg = __builtin_amdgcn_mfma_f32_16x16x32_bf16(ah0, w0f, cg, 0,0,0);
        cg = __builtin_amdgcn_mfma_f32_16x16x32_bf16(ah1, w1f, cg, 0,0,0);
        if (lc < 8) {
            #pragma unroll
            for (int reg = 0; reg < 4; ++reg)
                sGate[lg*4 + reg][lc] = 1.f / (1.f + __expf(-cg[reg]));
        }
    }
    __syncthreads();   // sGate ready; phase-A scratch dead -> reuse

    // ---- phase B: per-wave PE pipeline ----
    int g7 = lc & 7;
    short8 bW1[4], bWc[2], bW2;
    #pragma unroll
    for (int ct = 0; ct < 4; ++ct) bW1[ct] = *(const short8*)(W1frag + ct*512 + l*8);
    bWc[0] = *(const short8*)(Wcfrag + l*8);
    bWc[1] = *(const short8*)(Wcfrag + 512 + l*8);
    bW2 = *(const short8*)(W2frag + l*8);

    float bias1[4];
    #pragma unroll
    for (int ct = 0; ct < 4; ++ct) bias1[ct] = peb1f[16*ct + lc];
    float cvec_g = cvecg[g7];
    float bias3 = we_b2[g7];
    unsigned short* sXw = sXe + w*640;

    #pragma unroll
    for (int rt = 0; rt < 4; ++rt) {
        int n = n0 + w*4 + rt;
        // lazily compute + stage this tile's xe rows (lanes lg==rt own them)
        if (lg == rt) {
            unsigned int* dst = (unsigned int*)(sXw + lc*40);
            float dist = sqrtf(dx*dx + dy*dy + dz*dz);
            dst[0] = pack2bf(dx, dy);
            dst[1] = pack2bf(dz, dist);
            float sx, cx2, sy, cy2, sz, cz2;
            __sincosf(dx * 3.14159265358979f, &sx, &cx2);
            __sincosf(dy * 3.14159265358979f, &sy, &cy2);
            __sincosf(dz * 3.14159265358979f, &sz, &cz2);
            dst[2]  = pack2bf(sx, sy);
            dst[3]  = pack2bf(cx2, cy2);
            dst[10] = pack2bf(sz, cz2);
            #pragma unroll
            for (int fi = 1; fi < 4; ++fi) {
                float nsx = 2.f*sx*cx2, ncx = fmaf(-2.f*sx, sx, 1.f);
                float nsy = 2.f*sy*cy2, ncy = fmaf(-2.f*sy, sy, 1.f);
                float nsz = 2.f*sz*cz2, ncz = fmaf(-2.f*sz, sz, 1.f);
                dst[2 + 2*fi] = pack2bf(nsx, nsy);
                dst[3 + 2*fi] = pack2bf(ncx, ncy);
                dst[10 + fi]  = pack2bf(nsz, ncz);
                sx = nsx; cx2 = ncx; sy = nsy; cy2 = ncy; sz = nsz; cz2 = ncz;
            }
            dst[14] = 0u; dst[15] = 0u;
        }
        short8 a1 = *(const short8*)(sXw + lc*40 + lg*8);
        f32x4 c1[4];
        #pragma unroll
        for (int ct = 0; ct < 4; ++ct) {
            f32x4 z = {0.f, 0.f, 0.f, 0.f};
            c1[ct] = __builtin_amdgcn_mfma_f32_16x16x32_bf16(a1, bW1[ct], z, 0, 0, 0);
        }
        #pragma unroll
        for (int ct = 0; ct < 4; ++ct) {
            #pragma unroll
            for (int reg = 0; reg < 4; ++reg) {
                float h1 = fmaxf(c1[ct][reg] + bias1[ct], 0.f);
                sA2[w][(lg*4 + reg)*72 + 16*ct + lc] = f2bf(h1);
            }
        }
        int ids_r[4];
        #pragma unroll
        for (int reg = 0; reg < 4; ++reg) ids_r[reg] = sIds[w*64 + rt*16 + lg*4 + reg];
        float qwv = qw[(size_t)n*8 + g7];
        f32x4 c2;
        #pragma unroll
        for (int reg = 0; reg < 4; ++reg)
            c2[reg] = kw[(size_t)max(ids_r[reg],0)*8 + g7] - qwv + cvec_g;
        short8 a20 = *(const short8*)(sA2[w] + lc*72 + lg*8);
        short8 a21 = *(const short8*)(sA2[w] + lc*72 + 32 + lg*8);
        c2 = __builtin_amdgcn_mfma_f32_16x16x32_bf16(a20, bWc[0], c2, 0, 0, 0);
        c2 = __builtin_amdgcn_mfma_f32_16x16x32_bf16(a21, bWc[1], c2, 0, 0, 0);
        if (lc < 8) {
            #pragma unroll
            for (int reg = 0; reg < 4; ++reg)
                sAh2w[(lg*4 + reg)*8 + lc] = f2bf(fmaxf(c2[reg], 0.f));
        }
        short8 a3 = {0,0,0,0,0,0,0,0};
        if (l < 16) a3 = *(const short8*)(sAh2w + lc*8);
        f32x4 c3;
        #pragma unroll
        for (int reg = 0; reg < 4; ++reg) c3[reg] = bias3;
        c3 = __builtin_amdgcn_mfma_f32_16x16x32_bf16(a3, bW2, c3, 0, 0, 0);
        float gv = sGate[w*4 + rt][g7];
        float lgt[4];
        #pragma unroll
        for (int reg = 0; reg < 4; ++reg) lgt[reg] = c3[reg] * gv;
        float m = fmaxf(fmaxf(lgt[0], lgt[1]), fmaxf(lgt[2], lgt[3]));
        m = fmaxf(m, __shfl_xor(m, 16));
        m = fmaxf(m, __shfl_xor(m, 32));
        float e[4], s = 0.f;
        #pragma unroll
        for (int reg = 0; reg < 4; ++reg) { e[reg] = __expf(lgt[reg] - m); s += e[reg]; }
        s += __shfl_xor(s, 16);
        s += __shfl_xor(s, 32);
        float inv = 1.f / s;
        if (lc < 8) {
            float av[4];
            #pragma unroll
            for (int reg = 0; reg < 4; ++reg) {
                int idv = ids_r[reg];
                float mf = (idv >= 0) ? 1.f : ((idv == -1) ? 0.f : -1.f);
                av[reg] = e[reg] * inv * mf;
            }
            // layout [point][gh=lc][k2=lg*4+reg], stride 24
            unsigned int* d = (unsigned int*)(sAttnB + ((w*4 + rt)*8 + lc)*24 + lg*4);
            d[0] = pack2bf(av[0], av[1]);
            d[1] = pack2bf(av[2], av[3]);
        }
    }

    // ---- einsum: attn via 2x b128, late v-gather ----
    {
        int p = lg, kk = lc;
        int n2 = n0 + w*4 + p;
        const unsigned short* ab = sAttnB + ((w*4 + p)*8 + (kk >> 1))*24;
        short8 aa0 = *(const short8*)(ab);
        short8 aa1 = *(const short8*)(ab + 8);
        float4 o = make_float4(0.f, 0.f, 0.f, 0.f);
        #pragma unroll
        for (int k2 = 0; k2 < 16; ++k2) {
            int id2 = max(sIds[w*64 + p*16 + k2], 0);
            unsigned short ar = (k2 < 8) ? (unsigned short)aa0[k2] : (unsigned short)aa1[k2-8];
            float a = bflo((unsigned int)ar);
            uint2 u = *(const uint2*)(v_bf + (size_t)id2*64 + kk*4);
            o.x += a * bflo(u.x); o.y += a * bfhi(u.x);
            o.z += a * bflo(u.y); o.w += a * bfhi(u.y);
        }
        *(float4*)(out + (size_t)n2*64 + kk*4) = o;
    }
}

// ---------------------------------------------------------------------------
extern "C" void kernel_launch(void* const* d_in, const int* in_sizes, int n_in,
                              void* d_out, int out_size, void* d_ws, size_t ws_size,
                              hipStream_t stream)
{
    const float* feat  = (const float*)d_in[0];
    const float* coord = (const float*)d_in[1];
    const int*   ridx  = (const int*)d_in[2];
    const int*   offs  = (const int*)d_in[3];
    const float* Wq = (const float*)d_in[4];  const float* bq = (const float*)d_in[5];  const float* bnq = (const float*)d_in[6];
    const float* Wk = (const float*)d_in[7];  const float* bk = (const float*)d_in[8];  const float* bnk = (const float*)d_in[9];
    const float* Wv = (const float*)d_in[10]; const float* bv = (const float*)d_in[11];
    const float* pe_W1 = (const float*)d_in[12]; const float* pe_b1 = (const float*)d_in[13]; const float* pe_bn = (const float*)d_in[14];
    const float* pe_W2 = (const float*)d_in[15]; const float* pe_b2 = (const float*)d_in[16];
    const float* we_W1 = (const float*)d_in[17]; const float* we_b1 = (const float*)d_in[18]; const float* we_bn = (const float*)d_in[19];
    const float* we_W2 = (const float*)d_in[20]; const float* we_b2 = (const float*)d_in[21];
    const float* cg_W1 = (const float*)d_in[22]; const float* cg_b1 = (const float*)d_in[23]; const float* cg_bn = (const float*)d_in[24];
    const float* cg_W2 = (const float*)d_in[25]; const float* cg_b2 = (const float*)d_in[26];
    float* out = (float*)d_out;
    int N = in_sizes[0] / 64;

    // bf16 tables first (16B aligned at ws base)
    unsigned short* v_bf = (unsigned short*)d_ws;               // N*64
    unsigned short* q_bf = v_bf + (size_t)N*64;                 // N*64
    float* kwp   = (float*)(q_bf + (size_t)N*64);               // N*8
    float* qwp   = kwp + (size_t)N*8;                           // N*8
    float* segm  = qwp + (size_t)N*8;                           // 256
    float* peb1f = segm + 256;                                  // 64
    float* cvecg = peb1f + 64;                                  // 8
    float* cgb1f = cvecg + 8;                                   // 64
    float* biasqF= cgb1f + 64;                                  // 64
    float* biaskF= biasqF + 64;                                 // 64
    float* pad0  = biaskF + 64;                                 // 56 pad
    float* cgW1cF= pad0 + 56;                                   // 4096
    unsigned short* WqF     = (unsigned short*)(cgW1cF + 4096); // 4096
    unsigned short* WkF     = WqF + 4096;                       // 4096
    unsigned short* WvF     = WkF + 4096;                       // 4096
    unsigned short* weW1F   = WvF + 4096;                       // 1024
    unsigned short* cgW1aF  = weW1F + 1024;                     // 4096
    unsigned short* cgW1bF  = cgW1aF + 4096;                    // 4096
    unsigned short* cgW2F   = cgW1bF + 4096;                    // 1024
    unsigned short* W1frag  = cgW2F + 1024;                     // 2048
    unsigned short* Wcfrag  = W1frag + 2048;                    // 1024
    unsigned short* W2frag  = Wcfrag + 1024;                    // 512

    k_prep<<<1, 256, 0, stream>>>(pe_W1, pe_b1, pe_bn, pe_W2, pe_b2,
                                  we_W1, we_b1, we_bn, we_W2,
                                  cg_W1, cg_b1, cg_bn, cg_W2,
                                  Wq, bq, bnq, Wk, bk, bnk, Wv,
                                  peb1f, cvecg, cgb1f, biasqF, biaskF, cgW1cF, segm,
                                  WqF, WkF, WvF, weW1F, cgW1aF, cgW1bF, cgW2F,
                                  W1frag, Wcfrag, W2frag);
    k_qkv<<<N/64, 256, 0, stream>>>(feat, offs, WqF, WkF, WvF, weW1F,
                                    biasqF, biaskF, bv,
                                    v_bf, q_bf, kwp, qwp, segm);
    k_main<<<N/16, 256, 0, stream>>>(coord, ridx, v_bf, q_bf, kwp, qwp,
                                     peb1f, cvecg, we_b2, cg_b2,
                                     segm, cgW1cF, cgb1f, offs,
                                     W1frag, Wcfrag, W2frag,
                                     cgW1aF, cgW1bF, cgW2F, out);
}